// Round 4
// baseline (349.705 us; speedup 1.0000x reference)
//
#include <hip/hip_runtime.h>
#include <hip/hip_bf16.h>
#include <math.h>

typedef __attribute__((ext_vector_type(8))) short bf16x8;
typedef __attribute__((ext_vector_type(4))) short bf16x4;
typedef __attribute__((ext_vector_type(4))) float f32x4;

#define DEV static __device__ __forceinline__
#define LOG2E 1.4426950408889634f

DEV unsigned short f2bf(float f) {
  unsigned int u = __float_as_uint(f);
  u += 0x7FFFu + ((u >> 16) & 1u);   // RNE, inputs finite
  return (unsigned short)(u >> 16);
}
DEV unsigned short f2bf_hw(float f) {      // hot path: HW cvt (RNE)
  __hip_bfloat16 h = __float2bfloat16(f);
  return *reinterpret_cast<unsigned short*>(&h);
}
DEV float wsum(float v) { for (int o = 32; o; o >>= 1) v += __shfl_xor(v, o); return v; }
DEV float wmaxr(float v) { for (int o = 32; o; o >>= 1) v = fmaxf(v, __shfl_xor(v, o)); return v; }

// async global->LDS, 16B per lane; dest = wave-uniform base + lane*16
DEV void gload_lds16(const void* g, void* s) {
  __builtin_amdgcn_global_load_lds(
      (const __attribute__((address_space(1))) unsigned int*)g,
      (__attribute__((address_space(3))) unsigned int*)s, 16, 0, 0);
}

// ---------- weight-quant scale: per-row |w| sums ----------
__global__ __launch_bounds__(256) void wred_k(const float* __restrict__ qw,
                                              const float* __restrict__ ow,
                                              float* __restrict__ rowsum) {
  int row = blockIdx.x;  // 0..3071 -> qkv_w, 3072..4095 -> out_w
  const float* p = (row < 3072) ? (qw + (size_t)row * 1024)
                                : (ow + (size_t)(row - 3072) * 1024);
  f32x4 v = *(const f32x4*)&p[threadIdx.x * 4];
  float s = fabsf(v[0]) + fabsf(v[1]) + fabsf(v[2]) + fabsf(v[3]);
  s = wsum(s);
  __shared__ float sh[4];
  if ((threadIdx.x & 63) == 0) sh[threadIdx.x >> 6] = s;
  __syncthreads();
  if (threadIdx.x == 0) rowsum[row] = sh[0] + sh[1] + sh[2] + sh[3];
}

__global__ __launch_bounds__(256) void finalize_k(const float* __restrict__ rowsum,
                                                  float* __restrict__ scales) {
  float s1 = 0.f, s2 = 0.f;
  for (int i = threadIdx.x; i < 3072; i += 256) s1 += rowsum[i];
  for (int i = threadIdx.x; i < 1024; i += 256) s2 += rowsum[3072 + i];
  s1 = wsum(s1); s2 = wsum(s2);
  __shared__ float sh1[4], sh2[4];
  if ((threadIdx.x & 63) == 0) { sh1[threadIdx.x >> 6] = s1; sh2[threadIdx.x >> 6] = s2; }
  __syncthreads();
  if (threadIdx.x == 0) {
    float m1 = fmaxf((sh1[0] + sh1[1] + sh1[2] + sh1[3]) / (3072.f * 1024.f), 1e-5f);
    float m2 = fmaxf((sh2[0] + sh2[1] + sh2[2] + sh2[3]) / (1024.f * 1024.f), 1e-5f);
    scales[0] = m1; scales[1] = 1.f / m1;
    scales[2] = m2; scales[3] = 1.f / m2;
  }
}

// ternary-quantize both weight matrices -> bf16 (4.19M elems = 4096*256*4)
__global__ __launch_bounds__(256) void wquant_k(const float* __restrict__ qw,
                                                const float* __restrict__ ow,
                                                const float* __restrict__ scales,
                                                unsigned short* __restrict__ Wq,
                                                unsigned short* __restrict__ Wo) {
  int i0 = (blockIdx.x * 256 + threadIdx.x) * 4;
  if (i0 < 3072 * 1024) {
    f32x4 v = *(const f32x4*)&qw[i0];
    bf16x4 u;
    for (int j = 0; j < 4; j++)
      u[j] = (short)f2bf(fminf(fmaxf(rintf(v[j] * scales[1]), -1.f), 1.f) * scales[0]);
    *(bf16x4*)&Wq[i0] = u;
  } else {
    int k = i0 - 3072 * 1024;
    f32x4 v = *(const f32x4*)&ow[k];
    bf16x4 u;
    for (int j = 0; j < 4; j++)
      u[j] = (short)f2bf(fminf(fmaxf(rintf(v[j] * scales[3]), -1.f), 1.f) * scales[2]);
    *(bf16x4*)&Wo[k] = u;
  }
}

// ---------- ada = 1 + cond @ norm_w^T ----------
__global__ __launch_bounds__(256) void ada_k(const float* __restrict__ cond,
                                             const float* __restrict__ nw,
                                             float* __restrict__ ada) {
  int j = blockIdx.x * 4 + (threadIdx.x >> 6);
  int b = blockIdx.y;
  int l = threadIdx.x & 63;
  const float* cp = cond + b * 1024;
  const float* wp = nw + (size_t)j * 1024;
  float s = 0.f;
  for (int c = l; c < 1024; c += 64) s += cp[c] * wp[c];
  s = wsum(s);
  if (l == 0) ada[b * 1024 + j] = 1.f + s;
}

// ---------- RMSNorm(ada) + act_quant -> bf16 ----------
__global__ __launch_bounds__(256) void rmsq_k(const float* __restrict__ x,
                                              const float* __restrict__ ada,
                                              unsigned short* __restrict__ Aq) {
  int row = blockIdx.x;          // b*2048 + t
  int b = row >> 11;
  const float* xr = x + (size_t)row * 1024;
  const float* ar = ada + b * 1024;
  int t4 = threadIdx.x * 4;
  f32x4 v = *(const f32x4*)&xr[t4];
  float ss = v[0]*v[0] + v[1]*v[1] + v[2]*v[2] + v[3]*v[3];
  ss = wsum(ss);
  __shared__ float sh[4], sh2[4];
  if ((threadIdx.x & 63) == 0) sh[threadIdx.x >> 6] = ss;
  __syncthreads();
  float inv = rsqrtf((sh[0] + sh[1] + sh[2] + sh[3]) * (1.f / 1024.f) + 1e-6f);
  f32x4 a = *(const f32x4*)&ar[t4];
  float xn[4]; float mx = 0.f;
  for (int i = 0; i < 4; i++) { xn[i] = v[i] * a[i] * inv; mx = fmaxf(mx, fabsf(xn[i])); }
  mx = wmaxr(mx);
  if ((threadIdx.x & 63) == 0) sh2[threadIdx.x >> 6] = mx;
  __syncthreads();
  float rmax = fmaxf(fmaxf(sh2[0], sh2[1]), fmaxf(sh2[2], sh2[3]));
  float s = 127.f / fmaxf(rmax, 1e-5f);
  float is = 1.f / s;
  bf16x4 u;
  for (int i = 0; i < 4; i++)
    u[i] = (short)f2bf(fminf(fmaxf(rintf(xn[i] * s), -128.f), 127.f) * is);
  *(bf16x4*)&Aq[(size_t)row * 1024 + t4] = u;
}

// ---------- act_quant of attention output ----------
__global__ __launch_bounds__(256) void oquant_k(const float* __restrict__ of,
                                                unsigned short* __restrict__ Oq) {
  int row = blockIdx.x;
  const float* xr = of + (size_t)row * 1024;
  int t4 = threadIdx.x * 4;
  f32x4 v = *(const f32x4*)&xr[t4];
  float mx = fmaxf(fmaxf(fabsf(v[0]), fabsf(v[1])), fmaxf(fabsf(v[2]), fabsf(v[3])));
  mx = wmaxr(mx);
  __shared__ float sh[4];
  if ((threadIdx.x & 63) == 0) sh[threadIdx.x >> 6] = mx;
  __syncthreads();
  float rmax = fmaxf(fmaxf(sh[0], sh[1]), fmaxf(sh[2], sh[3]));
  float s = 127.f / fmaxf(rmax, 1e-5f);
  float is = 1.f / s;
  bf16x4 u;
  for (int i = 0; i < 4; i++)
    u[i] = (short)f2bf(fminf(fmaxf(rintf(v[i] * s), -128.f), 127.f) * is);
  *(bf16x4*)&Oq[(size_t)row * 1024 + t4] = u;
}

// ---------- C[M][N] = A[M][K] * B[N][K]^T, 128x128 tile, BK=64, gl_lds + XOR swizzle ----------
// LDS layout: row-major [128][64], granule(16B) index XORed with (row&7).
// global_load_lds writes linearly -> source fetches granule (l&7)^(l>>3) of its row.
__global__ __launch_bounds__(256) void gemm_bt(const unsigned short* __restrict__ A,
                                               const unsigned short* __restrict__ Bw,
                                               int N, int K, int mode,
                                               const float* __restrict__ skip,
                                               float* __restrict__ outF,
                                               unsigned short* __restrict__ outB) {
  __shared__ unsigned short As[128 * 64];
  __shared__ unsigned short Bs[128 * 64];
  int tid = threadIdx.x;
  int w = tid >> 6, l = tid & 63;
  int q = l & 15, g = l >> 4;
  int tm = blockIdx.x * 128, tn = blockIdx.y * 128;
  int wr = w >> 1, wc = w & 1;          // wave's 64x64 quadrant
  f32x4 zero = {0.f, 0.f, 0.f, 0.f};
  f32x4 acc[4][4];
  for (int m = 0; m < 4; m++) for (int n = 0; n < 4; n++) acc[m][n] = zero;
  int srow = l >> 3;                    // 0..7
  int sg = (l & 7) ^ srow;              // logical granule to fetch (inverse swizzle)
  const unsigned short* Ag = A + (size_t)(tm + srow) * K + sg * 8;
  const unsigned short* Bg = Bw + (size_t)(tn + srow) * K + sg * 8;
  for (int k0 = 0; k0 < K; k0 += 64) {
    for (int ra = 0; ra < 4; ra++) {    // wave w stages rows w*32+ra*8 .. +8
      size_t roff = (size_t)((w * 4 + ra) * 8) * K + k0;
      gload_lds16(Ag + roff, &As[(w * 4 + ra) * 512]);
      gload_lds16(Bg + roff, &Bs[(w * 4 + ra) * 512]);
    }
    __syncthreads();                    // drains vmcnt -> LDS ready
    for (int kk = 0; kk < 2; kk++) {
      int gs = ((kk * 4 + g) ^ (q & 7)) * 8;
      bf16x8 af[4], bfr[4];
      for (int m = 0; m < 4; m++)
        af[m] = *(const bf16x8*)&As[(wr * 64 + m * 16 + q) * 64 + gs];
      for (int n = 0; n < 4; n++)
        bfr[n] = *(const bf16x8*)&Bs[(wc * 64 + n * 16 + q) * 64 + gs];
      for (int m = 0; m < 4; m++)
        for (int n = 0; n < 4; n++)
          acc[m][n] = __builtin_amdgcn_mfma_f32_16x16x32_bf16(af[m], bfr[n], acc[m][n], 0, 0, 0);
    }
    __syncthreads();
  }
  for (int m = 0; m < 4; m++) {
    for (int n = 0; n < 4; n++) {
      int col = tn + wc * 64 + n * 16 + q;
      for (int r = 0; r < 4; r++) {
        int row = tm + wr * 64 + m * 16 + g * 4 + r;
        float vv = acc[m][n][r];
        if (mode == 0) outB[(size_t)row * N + col] = f2bf(vv);
        else { size_t idx = (size_t)row * N + col; outF[idx] = vv + skip[idx]; }
      }
    }
  }
}

// ---------- qk-norm + RoPE (Q pre-scaled by log2(e) for exp2-softmax) ----------
__global__ __launch_bounds__(256) void rope_k(const unsigned short* __restrict__ qkv,
                                              const float* __restrict__ pos,
                                              const float* __restrict__ scale,
                                              const float* __restrict__ freqs,
                                              unsigned short* __restrict__ Qo,
                                              unsigned short* __restrict__ Ko) {
  int tid = threadIdx.x;
  int w = tid >> 6, l = tid & 63;
  int gw = blockIdx.x * 4 + w;            // b*32768 + t*16 + h
  int h = gw & 15, t = (gw >> 4) & 2047, b = gw >> 15;
  const unsigned short* base = qkv + ((size_t)(b * 2048 + t)) * 3072 + h * 64 + l;
  float qv = __uint_as_float(((unsigned)base[0]) << 16);
  float kv = __uint_as_float(((unsigned)base[1024]) << 16);
  float sq = qv * qv, sk = kv * kv;
  for (int o = 32; o; o >>= 1) { sq += __shfl_xor(sq, o); sk += __shfl_xor(sk, o); }
  float ssc = sqrtf(scale[h]);
  float fq = ssc * rsqrtf(sq + 1e-6f);
  float fk = ssc * rsqrtf(sk + 1e-6f);
  float qn = qv * fq, kn = kv * fk;
  int e = l;
  int idx24 = (e < 24) ? e : e - 24;
  int partner = (e < 24) ? e + 24 : ((e < 48) ? e - 24 : e);
  float qo = __shfl(qn, partner), ko = __shfl(kn, partner);
  float qr = qn, kr = kn;
  if (e < 48) {
    int a = idx24 >> 3, f = idx24 & 7;
    float th = pos[((size_t)(b * 2048 + t)) * 3 + a] * freqs[h * 8 + f];
    float sn, cs; __sincosf(th, &sn, &cs);
    if (e < 24) { qr = qn * cs - qo * sn; kr = kn * cs - ko * sn; }
    else        { qr = qn * cs + qo * sn; kr = kn * cs + ko * sn; }
  }
  size_t oi = ((size_t)((b * 16 + h) * 2048 + t)) * 64 + e;
  Qo[oi] = f2bf(qr * LOG2E);   // pre-scale: softmax uses exp2
  Ko[oi] = f2bf(kr);
}

// ---------- V transpose: VT[b][h][e][t] ----------
__global__ __launch_bounds__(256) void vtrans_k(const unsigned short* __restrict__ qkv,
                                                unsigned short* __restrict__ VT) {
  __shared__ unsigned short tile[64][72];
  int tt = blockIdx.x, bh = blockIdx.y;
  int b = bh >> 4, h = bh & 15;
  int tid = threadIdx.x;
  for (int ro = 0; ro < 2; ro++) {
    int r = ro * 32 + (tid >> 3);
    int c = (tid & 7) * 8;
    *(bf16x8*)&tile[r][c] =
        *(const bf16x8*)(qkv + ((size_t)(b * 2048 + tt * 64 + r)) * 3072 + 2048 + h * 64 + c);
  }
  __syncthreads();
  int e = tid >> 2;
  int tc = (tid & 3) * 16;
  bf16x8 o0, o1;
  for (int i = 0; i < 8; i++) { o0[i] = (short)tile[tc + i][e]; o1[i] = (short)tile[tc + 8 + i][e]; }
  unsigned short* dst = VT + ((size_t)(bh * 64 + e)) * 2048 + tt * 64 + tc;
  *(bf16x8*)dst = o0;
  *(bf16x8*)(dst + 8) = o1;
}

// ---------- flash attention v3: gl_lds double-buffered K/V, swizzled LDS ----------
// grid 512 = 32 bh * 16 qg; block 256 = 4 waves; wave = 32 Q-rows
__global__ __launch_bounds__(256) void attn_k(const unsigned short* __restrict__ Q,
                                              const unsigned short* __restrict__ K,
                                              const unsigned short* __restrict__ VT,
                                              float* __restrict__ O) {
  __shared__ unsigned short KsB[2][64 * 64];   // [ktok][e], granule^=(row&7)
  __shared__ unsigned short VsB[2][64 * 64];   // [e][ktok], granule^=(row&7)
  __shared__ unsigned short Ps[4][32 * 64];    // per-wave P^T [qrow][ktok], swizzled
  int tid = threadIdx.x;
  int w = tid >> 6, l = tid & 63;
  int q = l & 15, g = l >> 4;
  int bh = blockIdx.x >> 4;
  int qg = blockIdx.x & 15;
  int qrow0 = qg * 128 + w * 32;
  const unsigned short* Kb = K + (size_t)bh * 2048 * 64;
  const unsigned short* Vb = VT + (size_t)bh * 64 * 2048;
  bf16x8 qa[2][2];
  for (int j = 0; j < 2; j++) {
    const unsigned short* Qp = Q + ((size_t)bh * 2048 + qrow0 + j * 16 + q) * 64 + g * 8;
    qa[j][0] = *(const bf16x8*)Qp;
    qa[j][1] = *(const bf16x8*)(Qp + 32);
  }
  int srow = l >> 3;
  int sg = (l & 7) ^ srow;               // inverse-swizzled source granule
  const unsigned short* KgL = Kb + (size_t)srow * 64 + sg * 8;
  const unsigned short* VgL = Vb + (size_t)srow * 2048 + sg * 8;
  unsigned short* PsW = &Ps[w][0];

  f32x4 zero = {0.f, 0.f, 0.f, 0.f};
  f32x4 acc[2][4];
  for (int j = 0; j < 2; j++) for (int e = 0; e < 4; e++) acc[j][e] = zero;
  float m[2] = {-INFINITY, -INFINITY};
  float sum[2] = {0.f, 0.f};

  auto stage = [&](int buf, int kt) {
    for (int i = 0; i < 2; i++) {
      gload_lds16(KgL + (size_t)(kt + (w * 2 + i) * 8) * 64, &KsB[buf][(w * 2 + i) * 512]);
      gload_lds16(VgL + (size_t)((w * 2 + i) * 8) * 2048 + kt, &VsB[buf][(w * 2 + i) * 512]);
    }
  };

  stage(0, 0);
  __syncthreads();
  int cur = 0;
  for (int kt = 0; kt < 2048; kt += 64) {
    if (kt + 64 < 2048) stage(cur ^ 1, kt + 64);   // T14: issue early
    const unsigned short* Ksc = KsB[cur];
    const unsigned short* Vsc = VsB[cur];
    // ---- QK^T: S^T[ktok][q] ----
    f32x4 s[2][4];
    for (int j = 0; j < 2; j++) for (int sub = 0; sub < 4; sub++) s[j][sub] = zero;
    for (int kk = 0; kk < 2; kk++) {
      int gsw = ((kk * 4 + g) ^ (q & 7)) * 8;
      for (int sub = 0; sub < 4; sub++) {
        bf16x8 ka = *(const bf16x8*)&Ksc[(sub * 16 + q) * 64 + gsw];
        s[0][sub] = __builtin_amdgcn_mfma_f32_16x16x32_bf16(ka, qa[0][kk], s[0][sub], 0, 0, 0);
        s[1][sub] = __builtin_amdgcn_mfma_f32_16x16x32_bf16(ka, qa[1][kk], s[1][sub], 0, 0, 0);
      }
    }
    // ---- online softmax (log2 domain, defer-max THR=8) ----
    for (int j = 0; j < 2; j++) {
      float tm = s[j][0][0];
      for (int sub = 0; sub < 4; sub++)
        for (int r = 0; r < 4; r++) tm = fmaxf(tm, s[j][sub][r]);
      tm = fmaxf(tm, __shfl_xor(tm, 16));
      tm = fmaxf(tm, __shfl_xor(tm, 32));
      if (!__all(tm - m[j] <= 8.f)) {
        float mn = fmaxf(m[j], tm);
        float alpha = exp2f(m[j] - mn);
        sum[j] *= alpha;
        for (int e = 0; e < 4; e++)
          for (int r = 0; r < 4; r++) acc[j][e][r] *= alpha;
        m[j] = mn;
      }
      float ts = 0.f;
      for (int sub = 0; sub < 4; sub++) {
        bf16x4 u;
        for (int r = 0; r < 4; r++) {
          float p = exp2f(s[j][sub][r] - m[j]);
          ts += p;
          u[r] = (short)f2bf_hw(p);
        }
        *(bf16x4*)&PsW[(j * 16 + q) * 64 + (((2 * sub + (g >> 1)) ^ (q & 7)) * 8) + (g & 1) * 4] = u;
      }
      ts += __shfl_xor(ts, 16);
      ts += __shfl_xor(ts, 32);
      sum[j] += ts;
    }
    __builtin_amdgcn_sched_barrier(0);   // Ps writes before reads
    // ---- PV: O^T += V^T . P^T ----
    for (int kk = 0; kk < 2; kk++) {
      int gsw = ((kk * 4 + g) ^ (q & 7)) * 8;
      bf16x8 pb0 = *(const bf16x8*)&PsW[q * 64 + gsw];
      bf16x8 pb1 = *(const bf16x8*)&PsW[(16 + q) * 64 + gsw];
      for (int eb = 0; eb < 4; eb++) {
        bf16x8 va = *(const bf16x8*)&Vsc[(eb * 16 + q) * 64 + gsw];
        acc[0][eb] = __builtin_amdgcn_mfma_f32_16x16x32_bf16(va, pb0, acc[0][eb], 0, 0, 0);
        acc[1][eb] = __builtin_amdgcn_mfma_f32_16x16x32_bf16(va, pb1, acc[1][eb], 0, 0, 0);
      }
    }
    __syncthreads();                     // drains prefetch vmcnt; buf swap safe
    cur ^= 1;
  }
  int b = bh >> 4, h = bh & 15;
  for (int j = 0; j < 2; j++) {
    float is = 1.f / sum[j];
    float* Op = O + ((size_t)(b * 2048 + qrow0 + j * 16 + q)) * 1024 + h * 64 + g * 4;
    for (int eb = 0; eb < 4; eb++) {
      f32x4 vvv;
      for (int r = 0; r < 4; r++) vvv[r] = acc[j][eb][r] * is;
      *(f32x4*)(Op + eb * 16) = vvv;
    }
  }
}

extern "C" void kernel_launch(void* const* d_in, const int* in_sizes, int n_in,
                              void* d_out, int out_size, void* d_ws, size_t ws_size,
                              hipStream_t stream) {
  const float* x      = (const float*)d_in[0];
  const float* pos    = (const float*)d_in[1];
  const float* cond   = (const float*)d_in[2];
  const float* norm_w = (const float*)d_in[3];
  const float* qkv_w  = (const float*)d_in[4];
  const float* out_w  = (const float*)d_in[5];
  const float* scale  = (const float*)d_in[6];
  const float* freqs  = (const float*)d_in[7];
  float* out = (float*)d_out;
  char* ws = (char*)d_ws;

  const size_t o_ada    = 0;
  const size_t o_rowsum = 8192;
  const size_t o_scales = 24576;
  const size_t o_Wq     = 24832;
  const size_t o_Wo     = o_Wq + 3072ull*1024*2;
  const size_t o_Aq     = o_Wo + 1024ull*1024*2;
  const size_t o_qkv    = o_Aq + 4096ull*1024*2;
  const size_t o_K      = o_qkv + 4096ull*3072*2;
  const size_t o_VT     = o_K + 2ull*16*2048*64*2;

  float* ada            = (float*)(ws + o_ada);
  float* rowsum         = (float*)(ws + o_rowsum);
  float* scales         = (float*)(ws + o_scales);
  unsigned short* Wq    = (unsigned short*)(ws + o_Wq);
  unsigned short* Wo    = (unsigned short*)(ws + o_Wo);
  unsigned short* Aq    = (unsigned short*)(ws + o_Aq);
  unsigned short* Qb    = Aq;                       // reuse after GEMM1
  unsigned short* qkv   = (unsigned short*)(ws + o_qkv);
  float* of             = (float*)(ws + o_qkv);     // reuse after rope/vtrans
  unsigned short* Kb    = (unsigned short*)(ws + o_K);
  unsigned short* Oq    = Kb;                       // reuse after attention
  unsigned short* VT    = (unsigned short*)(ws + o_VT);

  wred_k<<<4096, 256, 0, stream>>>(qkv_w, out_w, rowsum);
  finalize_k<<<1, 256, 0, stream>>>(rowsum, scales);
  wquant_k<<<4096, 256, 0, stream>>>(qkv_w, out_w, scales, Wq, Wo);
  ada_k<<<dim3(256, 2), 256, 0, stream>>>(cond, norm_w, ada);
  rmsq_k<<<4096, 256, 0, stream>>>(x, ada, Aq);
  gemm_bt<<<dim3(32, 24), 256, 0, stream>>>(Aq, Wq, 3072, 1024, 0, nullptr, nullptr, qkv);
  rope_k<<<16384, 256, 0, stream>>>(qkv, pos, scale, freqs, Qb, Kb);
  vtrans_k<<<dim3(32, 32), 256, 0, stream>>>(qkv, VT);
  attn_k<<<512, 256, 0, stream>>>(Qb, Kb, VT, of);
  oquant_k<<<4096, 256, 0, stream>>>(of, Oq);
  gemm_bt<<<dim3(32, 8), 256, 0, stream>>>(Oq, Wo, 1024, 1024, 1, x, out, nullptr);
}

// Round 5
// 195.406 us; speedup vs baseline: 1.7896x; 1.7896x over previous
//
#include <hip/hip_runtime.h>
#include <hip/hip_bf16.h>
#include <math.h>

typedef __attribute__((ext_vector_type(8))) short bf16x8;
typedef __attribute__((ext_vector_type(4))) short bf16x4;
typedef __attribute__((ext_vector_type(4))) float f32x4;

#define DEV static __device__ __forceinline__
#define LOG2E 1.4426950408889634f

DEV unsigned short f2bf(float f) {
  unsigned int u = __float_as_uint(f);
  u += 0x7FFFu + ((u >> 16) & 1u);   // RNE, inputs finite
  return (unsigned short)(u >> 16);
}
DEV unsigned short f2bf_hw(float f) {
  __hip_bfloat16 h = __float2bfloat16(f);
  return *reinterpret_cast<unsigned short*>(&h);
}
DEV float wsum(float v) { for (int o = 32; o; o >>= 1) v += __shfl_xor(v, o); return v; }
DEV float wmaxr(float v) { for (int o = 32; o; o >>= 1) v = fmaxf(v, __shfl_xor(v, o)); return v; }

// async global->LDS, 16B per lane; dest = wave-uniform base + lane*16
DEV void gload_lds16(const void* g, void* s) {
  __builtin_amdgcn_global_load_lds(
      (const __attribute__((address_space(1))) unsigned int*)g,
      (__attribute__((address_space(3))) unsigned int*)s, 16, 0, 0);
}

// ---------- weight-quant scale: per-row |w| sums ----------
__global__ __launch_bounds__(256) void wred_k(const float* __restrict__ qw,
                                              const float* __restrict__ ow,
                                              float* __restrict__ rowsum) {
  int row = blockIdx.x;  // 0..3071 -> qkv_w, 3072..4095 -> out_w
  const float* p = (row < 3072) ? (qw + (size_t)row * 1024)
                                : (ow + (size_t)(row - 3072) * 1024);
  f32x4 v = *(const f32x4*)&p[threadIdx.x * 4];
  float s = fabsf(v[0]) + fabsf(v[1]) + fabsf(v[2]) + fabsf(v[3]);
  s = wsum(s);
  __shared__ float sh[4];
  if ((threadIdx.x & 63) == 0) sh[threadIdx.x >> 6] = s;
  __syncthreads();
  if (threadIdx.x == 0) rowsum[row] = sh[0] + sh[1] + sh[2] + sh[3];
}

__global__ __launch_bounds__(256) void finalize_k(const float* __restrict__ rowsum,
                                                  float* __restrict__ scales) {
  float s1 = 0.f, s2 = 0.f;
  for (int i = threadIdx.x; i < 3072; i += 256) s1 += rowsum[i];
  for (int i = threadIdx.x; i < 1024; i += 256) s2 += rowsum[3072 + i];
  s1 = wsum(s1); s2 = wsum(s2);
  __shared__ float sh1[4], sh2[4];
  if ((threadIdx.x & 63) == 0) { sh1[threadIdx.x >> 6] = s1; sh2[threadIdx.x >> 6] = s2; }
  __syncthreads();
  if (threadIdx.x == 0) {
    float m1 = fmaxf((sh1[0] + sh1[1] + sh1[2] + sh1[3]) / (3072.f * 1024.f), 1e-5f);
    float m2 = fmaxf((sh2[0] + sh2[1] + sh2[2] + sh2[3]) / (1024.f * 1024.f), 1e-5f);
    scales[0] = m1; scales[1] = 1.f / m1;
    scales[2] = m2; scales[3] = 1.f / m2;
  }
}

// ternary-quantize both weight matrices -> bf16 (4.19M elems = 4096*256*4)
__global__ __launch_bounds__(256) void wquant_k(const float* __restrict__ qw,
                                                const float* __restrict__ ow,
                                                const float* __restrict__ scales,
                                                unsigned short* __restrict__ Wq,
                                                unsigned short* __restrict__ Wo) {
  int i0 = (blockIdx.x * 256 + threadIdx.x) * 4;
  if (i0 < 3072 * 1024) {
    f32x4 v = *(const f32x4*)&qw[i0];
    bf16x4 u;
    for (int j = 0; j < 4; j++)
      u[j] = (short)f2bf(fminf(fmaxf(rintf(v[j] * scales[1]), -1.f), 1.f) * scales[0]);
    *(bf16x4*)&Wq[i0] = u;
  } else {
    int k = i0 - 3072 * 1024;
    f32x4 v = *(const f32x4*)&ow[k];
    bf16x4 u;
    for (int j = 0; j < 4; j++)
      u[j] = (short)f2bf(fminf(fmaxf(rintf(v[j] * scales[3]), -1.f), 1.f) * scales[2]);
    *(bf16x4*)&Wo[k] = u;
  }
}

// ---------- ada = 1 + cond @ norm_w^T ----------
__global__ __launch_bounds__(256) void ada_k(const float* __restrict__ cond,
                                             const float* __restrict__ nw,
                                             float* __restrict__ ada) {
  int j = blockIdx.x * 4 + (threadIdx.x >> 6);
  int b = blockIdx.y;
  int l = threadIdx.x & 63;
  const float* cp = cond + b * 1024;
  const float* wp = nw + (size_t)j * 1024;
  float s = 0.f;
  for (int c = l; c < 1024; c += 64) s += cp[c] * wp[c];
  s = wsum(s);
  if (l == 0) ada[b * 1024 + j] = 1.f + s;
}

// ---------- RMSNorm(ada) + act_quant -> bf16 ----------
__global__ __launch_bounds__(256) void rmsq_k(const float* __restrict__ x,
                                              const float* __restrict__ ada,
                                              unsigned short* __restrict__ Aq) {
  int row = blockIdx.x;          // b*2048 + t
  int b = row >> 11;
  const float* xr = x + (size_t)row * 1024;
  const float* ar = ada + b * 1024;
  int t4 = threadIdx.x * 4;
  f32x4 v = *(const f32x4*)&xr[t4];
  float ss = v[0]*v[0] + v[1]*v[1] + v[2]*v[2] + v[3]*v[3];
  ss = wsum(ss);
  __shared__ float sh[4], sh2[4];
  if ((threadIdx.x & 63) == 0) sh[threadIdx.x >> 6] = ss;
  __syncthreads();
  float inv = rsqrtf((sh[0] + sh[1] + sh[2] + sh[3]) * (1.f / 1024.f) + 1e-6f);
  f32x4 a = *(const f32x4*)&ar[t4];
  float xn[4]; float mx = 0.f;
  for (int i = 0; i < 4; i++) { xn[i] = v[i] * a[i] * inv; mx = fmaxf(mx, fabsf(xn[i])); }
  mx = wmaxr(mx);
  if ((threadIdx.x & 63) == 0) sh2[threadIdx.x >> 6] = mx;
  __syncthreads();
  float rmax = fmaxf(fmaxf(sh2[0], sh2[1]), fmaxf(sh2[2], sh2[3]));
  float s = 127.f / fmaxf(rmax, 1e-5f);
  float is = 1.f / s;
  bf16x4 u;
  for (int i = 0; i < 4; i++)
    u[i] = (short)f2bf(fminf(fmaxf(rintf(xn[i] * s), -128.f), 127.f) * is);
  *(bf16x4*)&Aq[(size_t)row * 1024 + t4] = u;
}

// ---------- act_quant of attention output ----------
__global__ __launch_bounds__(256) void oquant_k(const float* __restrict__ of,
                                                unsigned short* __restrict__ Oq) {
  int row = blockIdx.x;
  const float* xr = of + (size_t)row * 1024;
  int t4 = threadIdx.x * 4;
  f32x4 v = *(const f32x4*)&xr[t4];
  float mx = fmaxf(fmaxf(fabsf(v[0]), fabsf(v[1])), fmaxf(fabsf(v[2]), fabsf(v[3])));
  mx = wmaxr(mx);
  __shared__ float sh[4];
  if ((threadIdx.x & 63) == 0) sh[threadIdx.x >> 6] = mx;
  __syncthreads();
  float rmax = fmaxf(fmaxf(sh[0], sh[1]), fmaxf(sh[2], sh[3]));
  float s = 127.f / fmaxf(rmax, 1e-5f);
  float is = 1.f / s;
  bf16x4 u;
  for (int i = 0; i < 4; i++)
    u[i] = (short)f2bf(fminf(fmaxf(rintf(v[i] * s), -128.f), 127.f) * is);
  *(bf16x4*)&Oq[(size_t)row * 1024 + t4] = u;
}

// ---------- C[M][N] = A[M][K] * B[N][K]^T, 128x128 tile, BK=64, gl_lds + XOR swizzle ----------
// __launch_bounds__(256,2): 256-VGPR budget -> no spill (R4: default heuristic gave
// 80 VGPR, spilled ~32 regs/thread -> 800 MB scratch writes, 151 us).
__global__ __launch_bounds__(256, 2) void gemm_bt(const unsigned short* __restrict__ A,
                                                  const unsigned short* __restrict__ Bw,
                                                  int N, int K, int mode,
                                                  const float* __restrict__ skip,
                                                  float* __restrict__ outF,
                                                  unsigned short* __restrict__ outB) {
  __shared__ unsigned short As[128 * 64];
  __shared__ unsigned short Bs[128 * 64];
  int tid = threadIdx.x;
  int w = tid >> 6, l = tid & 63;
  int q = l & 15, g = l >> 4;
  int tm = blockIdx.x * 128, tn = blockIdx.y * 128;
  int wr = w >> 1, wc = w & 1;          // wave's 64x64 quadrant
  f32x4 zero = {0.f, 0.f, 0.f, 0.f};
  f32x4 acc[4][4];
#pragma unroll
  for (int m = 0; m < 4; m++)
#pragma unroll
    for (int n = 0; n < 4; n++) acc[m][n] = zero;
  int srow = l >> 3;                    // 0..7
  int sg = (l & 7) ^ srow;              // inverse-swizzled source granule
  const unsigned short* Ag = A + (size_t)(tm + srow) * K + sg * 8;
  const unsigned short* Bg = Bw + (size_t)(tn + srow) * K + sg * 8;
  for (int k0 = 0; k0 < K; k0 += 64) {
#pragma unroll
    for (int ra = 0; ra < 4; ra++) {    // wave w stages rows w*32+ra*8 .. +8
      size_t roff = (size_t)((w * 4 + ra) * 8) * K + k0;
      gload_lds16(Ag + roff, &As[(w * 4 + ra) * 512]);
      gload_lds16(Bg + roff, &Bs[(w * 4 + ra) * 512]);
    }
    __syncthreads();                    // drains vmcnt -> LDS ready
#pragma unroll
    for (int kk = 0; kk < 2; kk++) {
      int gs = ((kk * 4 + g) ^ (q & 7)) * 8;
      bf16x8 af[4], bfr[4];
#pragma unroll
      for (int m = 0; m < 4; m++)
        af[m] = *(const bf16x8*)&As[(wr * 64 + m * 16 + q) * 64 + gs];
#pragma unroll
      for (int n = 0; n < 4; n++)
        bfr[n] = *(const bf16x8*)&Bs[(wc * 64 + n * 16 + q) * 64 + gs];
#pragma unroll
      for (int m = 0; m < 4; m++)
#pragma unroll
        for (int n = 0; n < 4; n++)
          acc[m][n] = __builtin_amdgcn_mfma_f32_16x16x32_bf16(af[m], bfr[n], acc[m][n], 0, 0, 0);
    }
    __syncthreads();
  }
#pragma unroll
  for (int m = 0; m < 4; m++) {
#pragma unroll
    for (int n = 0; n < 4; n++) {
      int col = tn + wc * 64 + n * 16 + q;
#pragma unroll
      for (int r = 0; r < 4; r++) {
        int row = tm + wr * 64 + m * 16 + g * 4 + r;
        float vv = acc[m][n][r];
        if (mode == 0) outB[(size_t)row * N + col] = f2bf(vv);
        else { size_t idx = (size_t)row * N + col; outF[idx] = vv + skip[idx]; }
      }
    }
  }
}

// ---------- qk-norm + RoPE (Q pre-scaled by log2(e) for exp2-softmax) ----------
__global__ __launch_bounds__(256) void rope_k(const unsigned short* __restrict__ qkv,
                                              const float* __restrict__ pos,
                                              const float* __restrict__ scale,
                                              const float* __restrict__ freqs,
                                              unsigned short* __restrict__ Qo,
                                              unsigned short* __restrict__ Ko) {
  int tid = threadIdx.x;
  int w = tid >> 6, l = tid & 63;
  int gw = blockIdx.x * 4 + w;            // b*32768 + t*16 + h
  int h = gw & 15, t = (gw >> 4) & 2047, b = gw >> 15;
  const unsigned short* base = qkv + ((size_t)(b * 2048 + t)) * 3072 + h * 64 + l;
  float qv = __uint_as_float(((unsigned)base[0]) << 16);
  float kv = __uint_as_float(((unsigned)base[1024]) << 16);
  float sq = qv * qv, sk = kv * kv;
  for (int o = 32; o; o >>= 1) { sq += __shfl_xor(sq, o); sk += __shfl_xor(sk, o); }
  float ssc = sqrtf(scale[h]);
  float fq = ssc * rsqrtf(sq + 1e-6f);
  float fk = ssc * rsqrtf(sk + 1e-6f);
  float qn = qv * fq, kn = kv * fk;
  int e = l;
  int idx24 = (e < 24) ? e : e - 24;
  int partner = (e < 24) ? e + 24 : ((e < 48) ? e - 24 : e);
  float qo = __shfl(qn, partner), ko = __shfl(kn, partner);
  float qr = qn, kr = kn;
  if (e < 48) {
    int a = idx24 >> 3, f = idx24 & 7;
    float th = pos[((size_t)(b * 2048 + t)) * 3 + a] * freqs[h * 8 + f];
    float sn, cs; __sincosf(th, &sn, &cs);
    if (e < 24) { qr = qn * cs - qo * sn; kr = kn * cs - ko * sn; }
    else        { qr = qn * cs + qo * sn; kr = kn * cs + ko * sn; }
  }
  size_t oi = ((size_t)((b * 16 + h) * 2048 + t)) * 64 + e;
  Qo[oi] = f2bf(qr * LOG2E);   // pre-scale: softmax uses exp2
  Ko[oi] = f2bf(kr);
}

// ---------- V transpose: VT[b][h][e][t] ----------
__global__ __launch_bounds__(256) void vtrans_k(const unsigned short* __restrict__ qkv,
                                                unsigned short* __restrict__ VT) {
  __shared__ unsigned short tile[64][72];
  int tt = blockIdx.x, bh = blockIdx.y;
  int b = bh >> 4, h = bh & 15;
  int tid = threadIdx.x;
  for (int ro = 0; ro < 2; ro++) {
    int r = ro * 32 + (tid >> 3);
    int c = (tid & 7) * 8;
    *(bf16x8*)&tile[r][c] =
        *(const bf16x8*)(qkv + ((size_t)(b * 2048 + tt * 64 + r)) * 3072 + 2048 + h * 64 + c);
  }
  __syncthreads();
  int e = tid >> 2;
  int tc = (tid & 3) * 16;
  bf16x8 o0, o1;
  for (int i = 0; i < 8; i++) { o0[i] = (short)tile[tc + i][e]; o1[i] = (short)tile[tc + 8 + i][e]; }
  unsigned short* dst = VT + ((size_t)(bh * 64 + e)) * 2048 + tt * 64 + tc;
  *(bf16x8*)dst = o0;
  *(bf16x8*)(dst + 8) = o1;
}

// ---------- flash attention v3: gl_lds double-buffered K/V, swizzled LDS ----------
__global__ __launch_bounds__(256, 2) void attn_k(const unsigned short* __restrict__ Q,
                                                 const unsigned short* __restrict__ K,
                                                 const unsigned short* __restrict__ VT,
                                                 float* __restrict__ O) {
  __shared__ unsigned short KsB[2][64 * 64];   // [ktok][e], granule^=(row&7)
  __shared__ unsigned short VsB[2][64 * 64];   // [e][ktok], granule^=(row&7)
  __shared__ unsigned short Ps[4][32 * 64];    // per-wave P^T [qrow][ktok], swizzled
  int tid = threadIdx.x;
  int w = tid >> 6, l = tid & 63;
  int q = l & 15, g = l >> 4;
  int bh = blockIdx.x >> 4;
  int qg = blockIdx.x & 15;
  int qrow0 = qg * 128 + w * 32;
  const unsigned short* Kb = K + (size_t)bh * 2048 * 64;
  const unsigned short* Vb = VT + (size_t)bh * 64 * 2048;
  bf16x8 qa[2][2];
#pragma unroll
  for (int j = 0; j < 2; j++) {
    const unsigned short* Qp = Q + ((size_t)bh * 2048 + qrow0 + j * 16 + q) * 64 + g * 8;
    qa[j][0] = *(const bf16x8*)Qp;
    qa[j][1] = *(const bf16x8*)(Qp + 32);
  }
  int srow = l >> 3;
  int sg = (l & 7) ^ srow;               // inverse-swizzled source granule
  const unsigned short* KgL = Kb + (size_t)srow * 64 + sg * 8;
  const unsigned short* VgL = Vb + (size_t)srow * 2048 + sg * 8;
  unsigned short* PsW = &Ps[w][0];

  f32x4 zero = {0.f, 0.f, 0.f, 0.f};
  f32x4 acc[2][4];
#pragma unroll
  for (int j = 0; j < 2; j++)
#pragma unroll
    for (int e = 0; e < 4; e++) acc[j][e] = zero;
  float m[2] = {-INFINITY, -INFINITY};
  float sum[2] = {0.f, 0.f};

  auto stage = [&](int buf, int kt) {
#pragma unroll
    for (int i = 0; i < 2; i++) {
      gload_lds16(KgL + (size_t)(kt + (w * 2 + i) * 8) * 64, &KsB[buf][(w * 2 + i) * 512]);
      gload_lds16(VgL + (size_t)((w * 2 + i) * 8) * 2048 + kt, &VsB[buf][(w * 2 + i) * 512]);
    }
  };

  stage(0, 0);
  __syncthreads();
  int cur = 0;
  for (int kt = 0; kt < 2048; kt += 64) {
    if (kt + 64 < 2048) stage(cur ^ 1, kt + 64);   // T14: issue early
    const unsigned short* Ksc = KsB[cur];
    const unsigned short* Vsc = VsB[cur];
    // ---- QK^T: S^T[ktok][q] ----
    f32x4 s[2][4];
#pragma unroll
    for (int j = 0; j < 2; j++)
#pragma unroll
      for (int sub = 0; sub < 4; sub++) s[j][sub] = zero;
#pragma unroll
    for (int kk = 0; kk < 2; kk++) {
      int gsw = ((kk * 4 + g) ^ (q & 7)) * 8;
#pragma unroll
      for (int sub = 0; sub < 4; sub++) {
        bf16x8 ka = *(const bf16x8*)&Ksc[(sub * 16 + q) * 64 + gsw];
        s[0][sub] = __builtin_amdgcn_mfma_f32_16x16x32_bf16(ka, qa[0][kk], s[0][sub], 0, 0, 0);
        s[1][sub] = __builtin_amdgcn_mfma_f32_16x16x32_bf16(ka, qa[1][kk], s[1][sub], 0, 0, 0);
      }
    }
    // ---- online softmax (log2 domain, defer-max THR=8) ----
#pragma unroll
    for (int j = 0; j < 2; j++) {
      float tm = s[j][0][0];
#pragma unroll
      for (int sub = 0; sub < 4; sub++)
#pragma unroll
        for (int r = 0; r < 4; r++) tm = fmaxf(tm, s[j][sub][r]);
      tm = fmaxf(tm, __shfl_xor(tm, 16));
      tm = fmaxf(tm, __shfl_xor(tm, 32));
      if (!__all(tm - m[j] <= 8.f)) {
        float mn = fmaxf(m[j], tm);
        float alpha = exp2f(m[j] - mn);
        sum[j] *= alpha;
#pragma unroll
        for (int e = 0; e < 4; e++)
#pragma unroll
          for (int r = 0; r < 4; r++) acc[j][e][r] *= alpha;
        m[j] = mn;
      }
      float ts = 0.f;
#pragma unroll
      for (int sub = 0; sub < 4; sub++) {
        bf16x4 u;
#pragma unroll
        for (int r = 0; r < 4; r++) {
          float p = exp2f(s[j][sub][r] - m[j]);
          ts += p;
          u[r] = (short)f2bf_hw(p);
        }
        *(bf16x4*)&PsW[(j * 16 + q) * 64 + (((2 * sub + (g >> 1)) ^ (q & 7)) * 8) + (g & 1) * 4] = u;
      }
      ts += __shfl_xor(ts, 16);
      ts += __shfl_xor(ts, 32);
      sum[j] += ts;
    }
    __builtin_amdgcn_sched_barrier(0);   // Ps writes before reads
    // ---- PV: O^T += V^T . P^T ----
#pragma unroll
    for (int kk = 0; kk < 2; kk++) {
      int gsw = ((kk * 4 + g) ^ (q & 7)) * 8;
      bf16x8 pb0 = *(const bf16x8*)&PsW[q * 64 + gsw];
      bf16x8 pb1 = *(const bf16x8*)&PsW[(16 + q) * 64 + gsw];
#pragma unroll
      for (int eb = 0; eb < 4; eb++) {
        bf16x8 va = *(const bf16x8*)&Vsc[(eb * 16 + q) * 64 + gsw];
        acc[0][eb] = __builtin_amdgcn_mfma_f32_16x16x32_bf16(va, pb0, acc[0][eb], 0, 0, 0);
        acc[1][eb] = __builtin_amdgcn_mfma_f32_16x16x32_bf16(va, pb1, acc[1][eb], 0, 0, 0);
      }
    }
    __syncthreads();                     // drains prefetch vmcnt; buf swap safe
    cur ^= 1;
  }
  int b = bh >> 4, h = bh & 15;
#pragma unroll
  for (int j = 0; j < 2; j++) {
    float is = 1.f / sum[j];
    float* Op = O + ((size_t)(b * 2048 + qrow0 + j * 16 + q)) * 1024 + h * 64 + g * 4;
#pragma unroll
    for (int eb = 0; eb < 4; eb++) {
      f32x4 vvv;
#pragma unroll
      for (int r = 0; r < 4; r++) vvv[r] = acc[j][eb][r] * is;
      *(f32x4*)(Op + eb * 16) = vvv;
    }
  }
}

extern "C" void kernel_launch(void* const* d_in, const int* in_sizes, int n_in,
                              void* d_out, int out_size, void* d_ws, size_t ws_size,
                              hipStream_t stream) {
  const float* x      = (const float*)d_in[0];
  const float* pos    = (const float*)d_in[1];
  const float* cond   = (const float*)d_in[2];
  const float* norm_w = (const float*)d_in[3];
  const float* qkv_w  = (const float*)d_in[4];
  const float* out_w  = (const float*)d_in[5];
  const float* scale  = (const float*)d_in[6];
  const float* freqs  = (const float*)d_in[7];
  float* out = (float*)d_out;
  char* ws = (char*)d_ws;

  const size_t o_ada    = 0;
  const size_t o_rowsum = 8192;
  const size_t o_scales = 24576;
  const size_t o_Wq     = 24832;
  const size_t o_Wo     = o_Wq + 3072ull*1024*2;
  const size_t o_Aq     = o_Wo + 1024ull*1024*2;
  const size_t o_qkv    = o_Aq + 4096ull*1024*2;
  const size_t o_K      = o_qkv + 4096ull*3072*2;
  const size_t o_VT     = o_K + 2ull*16*2048*64*2;

  float* ada            = (float*)(ws + o_ada);
  float* rowsum         = (float*)(ws + o_rowsum);
  float* scales         = (float*)(ws + o_scales);
  unsigned short* Wq    = (unsigned short*)(ws + o_Wq);
  unsigned short* Wo    = (unsigned short*)(ws + o_Wo);
  unsigned short* Aq    = (unsigned short*)(ws + o_Aq);
  unsigned short* Qb    = Aq;                       // reuse after GEMM1
  unsigned short* qkv   = (unsigned short*)(ws + o_qkv);
  float* of             = (float*)(ws + o_qkv);     // reuse after rope/vtrans
  unsigned short* Kb    = (unsigned short*)(ws + o_K);
  unsigned short* Oq    = Kb;                       // reuse after attention
  unsigned short* VT    = (unsigned short*)(ws + o_VT);

  wred_k<<<4096, 256, 0, stream>>>(qkv_w, out_w, rowsum);
  finalize_k<<<1, 256, 0, stream>>>(rowsum, scales);
  wquant_k<<<4096, 256, 0, stream>>>(qkv_w, out_w, scales, Wq, Wo);
  ada_k<<<dim3(256, 2), 256, 0, stream>>>(cond, norm_w, ada);
  rmsq_k<<<4096, 256, 0, stream>>>(x, ada, Aq);
  gemm_bt<<<dim3(32, 24), 256, 0, stream>>>(Aq, Wq, 3072, 1024, 0, nullptr, nullptr, qkv);
  rope_k<<<16384, 256, 0, stream>>>(qkv, pos, scale, freqs, Qb, Kb);
  vtrans_k<<<dim3(32, 32), 256, 0, stream>>>(qkv, VT);
  attn_k<<<512, 256, 0, stream>>>(Qb, Kb, VT, of);
  oquant_k<<<4096, 256, 0, stream>>>(of, Oq);
  gemm_bt<<<dim3(32, 8), 256, 0, stream>>>(Oq, Wo, 1024, 1024, 1, x, out, nullptr);
}

// Round 6
// 188.900 us; speedup vs baseline: 1.8513x; 1.0344x over previous
//
#include <hip/hip_runtime.h>
#include <hip/hip_bf16.h>
#include <math.h>

typedef __attribute__((ext_vector_type(8))) short bf16x8;
typedef __attribute__((ext_vector_type(4))) short bf16x4;
typedef __attribute__((ext_vector_type(4))) float f32x4;
typedef __attribute__((ext_vector_type(16))) float f32x16;
typedef __attribute__((ext_vector_type(4))) int i32x4;

#define DEV static __device__ __forceinline__
#define LOG2E 1.4426950408889634f

DEV unsigned short f2bf(float f) {
  unsigned int u = __float_as_uint(f);
  u += 0x7FFFu + ((u >> 16) & 1u);   // RNE, inputs finite
  return (unsigned short)(u >> 16);
}
DEV unsigned short f2bf_hw(float f) {
  __hip_bfloat16 h = __float2bfloat16(f);
  return *reinterpret_cast<unsigned short*>(&h);
}
DEV float bf2f(unsigned short h) { return __uint_as_float(((unsigned int)h) << 16); }
DEV float wsum(float v) { for (int o = 32; o; o >>= 1) v += __shfl_xor(v, o); return v; }
DEV float wmaxr(float v) { for (int o = 32; o; o >>= 1) v = fmaxf(v, __shfl_xor(v, o)); return v; }

// async global->LDS, 16B per lane; dest = wave-uniform base + lane*16
DEV void gload_lds16(const void* g, void* s) {
  __builtin_amdgcn_global_load_lds(
      (const __attribute__((address_space(1))) unsigned int*)g,
      (__attribute__((address_space(3))) unsigned int*)s, 16, 0, 0);
}

// ---------- weight-quant scale: per-row |w| sums ----------
__global__ __launch_bounds__(256) void wred_k(const float* __restrict__ qw,
                                              const float* __restrict__ ow,
                                              float* __restrict__ rowsum) {
  int row = blockIdx.x;  // 0..3071 -> qkv_w, 3072..4095 -> out_w
  const float* p = (row < 3072) ? (qw + (size_t)row * 1024)
                                : (ow + (size_t)(row - 3072) * 1024);
  f32x4 v = *(const f32x4*)&p[threadIdx.x * 4];
  float s = fabsf(v[0]) + fabsf(v[1]) + fabsf(v[2]) + fabsf(v[3]);
  s = wsum(s);
  __shared__ float sh[4];
  if ((threadIdx.x & 63) == 0) sh[threadIdx.x >> 6] = s;
  __syncthreads();
  if (threadIdx.x == 0) rowsum[row] = sh[0] + sh[1] + sh[2] + sh[3];
}

__global__ __launch_bounds__(256) void finalize_k(const float* __restrict__ rowsum,
                                                  float* __restrict__ scales) {
  float s1 = 0.f, s2 = 0.f;
  for (int i = threadIdx.x; i < 3072; i += 256) s1 += rowsum[i];
  for (int i = threadIdx.x; i < 1024; i += 256) s2 += rowsum[3072 + i];
  s1 = wsum(s1); s2 = wsum(s2);
  __shared__ float sh1[4], sh2[4];
  if ((threadIdx.x & 63) == 0) { sh1[threadIdx.x >> 6] = s1; sh2[threadIdx.x >> 6] = s2; }
  __syncthreads();
  if (threadIdx.x == 0) {
    float m1 = fmaxf((sh1[0] + sh1[1] + sh1[2] + sh1[3]) / (3072.f * 1024.f), 1e-5f);
    float m2 = fmaxf((sh2[0] + sh2[1] + sh2[2] + sh2[3]) / (1024.f * 1024.f), 1e-5f);
    scales[0] = m1; scales[1] = 1.f / m1;
    scales[2] = m2; scales[3] = 1.f / m2;
  }
}

// ternary-quantize both weight matrices -> bf16 (4.19M elems = 4096*256*4)
__global__ __launch_bounds__(256) void wquant_k(const float* __restrict__ qw,
                                                const float* __restrict__ ow,
                                                const float* __restrict__ scales,
                                                unsigned short* __restrict__ Wq,
                                                unsigned short* __restrict__ Wo) {
  int i0 = (blockIdx.x * 256 + threadIdx.x) * 4;
  if (i0 < 3072 * 1024) {
    f32x4 v = *(const f32x4*)&qw[i0];
    bf16x4 u;
    for (int j = 0; j < 4; j++)
      u[j] = (short)f2bf(fminf(fmaxf(rintf(v[j] * scales[1]), -1.f), 1.f) * scales[0]);
    *(bf16x4*)&Wq[i0] = u;
  } else {
    int k = i0 - 3072 * 1024;
    f32x4 v = *(const f32x4*)&ow[k];
    bf16x4 u;
    for (int j = 0; j < 4; j++)
      u[j] = (short)f2bf(fminf(fmaxf(rintf(v[j] * scales[3]), -1.f), 1.f) * scales[2]);
    *(bf16x4*)&Wo[k] = u;
  }
}

// ---------- ada = 1 + cond @ norm_w^T ----------
__global__ __launch_bounds__(256) void ada_k(const float* __restrict__ cond,
                                             const float* __restrict__ nw,
                                             float* __restrict__ ada) {
  int j = blockIdx.x * 4 + (threadIdx.x >> 6);
  int b = blockIdx.y;
  int l = threadIdx.x & 63;
  const float* cp = cond + b * 1024;
  const float* wp = nw + (size_t)j * 1024;
  float s = 0.f;
  for (int c = l; c < 1024; c += 64) s += cp[c] * wp[c];
  s = wsum(s);
  if (l == 0) ada[b * 1024 + j] = 1.f + s;
}

// ---------- RMSNorm(ada) + act_quant -> bf16 ----------
__global__ __launch_bounds__(256) void rmsq_k(const float* __restrict__ x,
                                              const float* __restrict__ ada,
                                              unsigned short* __restrict__ Aq) {
  int row = blockIdx.x;          // b*2048 + t
  int b = row >> 11;
  const float* xr = x + (size_t)row * 1024;
  const float* ar = ada + b * 1024;
  int t4 = threadIdx.x * 4;
  f32x4 v = *(const f32x4*)&xr[t4];
  float ss = v[0]*v[0] + v[1]*v[1] + v[2]*v[2] + v[3]*v[3];
  ss = wsum(ss);
  __shared__ float sh[4], sh2[4];
  if ((threadIdx.x & 63) == 0) sh[threadIdx.x >> 6] = ss;
  __syncthreads();
  float inv = rsqrtf((sh[0] + sh[1] + sh[2] + sh[3]) * (1.f / 1024.f) + 1e-6f);
  f32x4 a = *(const f32x4*)&ar[t4];
  float xn[4]; float mx = 0.f;
  for (int i = 0; i < 4; i++) { xn[i] = v[i] * a[i] * inv; mx = fmaxf(mx, fabsf(xn[i])); }
  mx = wmaxr(mx);
  if ((threadIdx.x & 63) == 0) sh2[threadIdx.x >> 6] = mx;
  __syncthreads();
  float rmax = fmaxf(fmaxf(sh2[0], sh2[1]), fmaxf(sh2[2], sh2[3]));
  float s = 127.f / fmaxf(rmax, 1e-5f);
  float is = 1.f / s;
  bf16x4 u;
  for (int i = 0; i < 4; i++)
    u[i] = (short)f2bf(fminf(fmaxf(rintf(xn[i] * s), -128.f), 127.f) * is);
  *(bf16x4*)&Aq[(size_t)row * 1024 + t4] = u;
}

// ---------- combine split-K partials + act_quant ----------
__global__ __launch_bounds__(256) void oquant_k(const unsigned short* __restrict__ Opart,
                                                const float* __restrict__ ms,
                                                unsigned short* __restrict__ Oq) {
  int row = blockIdx.x;            // b*2048 + t
  int b = row >> 11, qrow = row & 2047;
  int t4 = threadIdx.x * 4;
  int h = t4 >> 6, e0 = t4 & 63;
  int bh = b * 16 + h;
  size_t i0 = (size_t)bh * 2048 + qrow;             // split 0
  size_t i1 = (size_t)(32 + bh) * 2048 + qrow;      // split 1
  float m0 = ms[i0 * 2], s0 = ms[i0 * 2 + 1];
  float m1 = ms[i1 * 2], s1 = ms[i1 * 2 + 1];
  float mm = fmaxf(m0, m1);
  float a0 = exp2f(m0 - mm), a1 = exp2f(m1 - mm);
  float den = s0 * a0 + s1 * a1;
  float w0 = a0 / den, w1 = a1 / den;
  bf16x4 o0 = *(const bf16x4*)&Opart[i0 * 64 + e0];
  bf16x4 o1 = *(const bf16x4*)&Opart[i1 * 64 + e0];
  float v[4]; float mx = 0.f;
  for (int i = 0; i < 4; i++) {
    v[i] = bf2f((unsigned short)o0[i]) * w0 + bf2f((unsigned short)o1[i]) * w1;
    mx = fmaxf(mx, fabsf(v[i]));
  }
  mx = wmaxr(mx);
  __shared__ float sh[4];
  if ((threadIdx.x & 63) == 0) sh[threadIdx.x >> 6] = mx;
  __syncthreads();
  float rmax = fmaxf(fmaxf(sh[0], sh[1]), fmaxf(sh[2], sh[3]));
  float s = 127.f / fmaxf(rmax, 1e-5f);
  float is = 1.f / s;
  bf16x4 u;
  for (int i = 0; i < 4; i++)
    u[i] = (short)f2bf(fminf(fmaxf(rintf(v[i] * s), -128.f), 127.f) * is);
  *(bf16x4*)&Oq[(size_t)row * 1024 + t4] = u;
}

// ---------- C[M][N] = A[M][K] * B[N][K]^T, 128x128 tile, BK=64, gl_lds + XOR swizzle ----------
__global__ __launch_bounds__(256, 2) void gemm_bt(const unsigned short* __restrict__ A,
                                                  const unsigned short* __restrict__ Bw,
                                                  int N, int K, int mode,
                                                  const float* __restrict__ skip,
                                                  float* __restrict__ outF,
                                                  unsigned short* __restrict__ outB) {
  __shared__ unsigned short As[128 * 64];
  __shared__ unsigned short Bs[128 * 64];
  int tid = threadIdx.x;
  int w = tid >> 6, l = tid & 63;
  int q = l & 15, g = l >> 4;
  int tm = blockIdx.x * 128, tn = blockIdx.y * 128;
  int wr = w >> 1, wc = w & 1;          // wave's 64x64 quadrant
  f32x4 zero = {0.f, 0.f, 0.f, 0.f};
  f32x4 acc[4][4];
#pragma unroll
  for (int m = 0; m < 4; m++)
#pragma unroll
    for (int n = 0; n < 4; n++) acc[m][n] = zero;
  int srow = l >> 3;
  int sg = (l & 7) ^ srow;              // inverse-swizzled source granule
  const unsigned short* Ag = A + (size_t)(tm + srow) * K + sg * 8;
  const unsigned short* Bg = Bw + (size_t)(tn + srow) * K + sg * 8;
  for (int k0 = 0; k0 < K; k0 += 64) {
#pragma unroll
    for (int ra = 0; ra < 4; ra++) {
      size_t roff = (size_t)((w * 4 + ra) * 8) * K + k0;
      gload_lds16(Ag + roff, &As[(w * 4 + ra) * 512]);
      gload_lds16(Bg + roff, &Bs[(w * 4 + ra) * 512]);
    }
    __syncthreads();
#pragma unroll
    for (int kk = 0; kk < 2; kk++) {
      int gs = ((kk * 4 + g) ^ (q & 7)) * 8;
      bf16x8 af[4], bfr[4];
#pragma unroll
      for (int m = 0; m < 4; m++)
        af[m] = *(const bf16x8*)&As[(wr * 64 + m * 16 + q) * 64 + gs];
#pragma unroll
      for (int n = 0; n < 4; n++)
        bfr[n] = *(const bf16x8*)&Bs[(wc * 64 + n * 16 + q) * 64 + gs];
#pragma unroll
      for (int m = 0; m < 4; m++)
#pragma unroll
        for (int n = 0; n < 4; n++)
          acc[m][n] = __builtin_amdgcn_mfma_f32_16x16x32_bf16(af[m], bfr[n], acc[m][n], 0, 0, 0);
    }
    __syncthreads();
  }
#pragma unroll
  for (int m = 0; m < 4; m++) {
#pragma unroll
    for (int n = 0; n < 4; n++) {
      int col = tn + wc * 64 + n * 16 + q;
#pragma unroll
      for (int r = 0; r < 4; r++) {
        int row = tm + wr * 64 + m * 16 + g * 4 + r;
        float vv = acc[m][n][r];
        if (mode == 0) outB[(size_t)row * N + col] = f2bf(vv);
        else { size_t idx = (size_t)row * N + col; outF[idx] = vv + skip[idx]; }
      }
    }
  }
}

// ---------- qk-norm + RoPE (Q pre-scaled by log2(e) for exp2-softmax) ----------
__global__ __launch_bounds__(256) void rope_k(const unsigned short* __restrict__ qkv,
                                              const float* __restrict__ pos,
                                              const float* __restrict__ scale,
                                              const float* __restrict__ freqs,
                                              unsigned short* __restrict__ Qo,
                                              unsigned short* __restrict__ Ko) {
  int tid = threadIdx.x;
  int w = tid >> 6, l = tid & 63;
  int gw = blockIdx.x * 4 + w;            // b*32768 + t*16 + h
  int h = gw & 15, t = (gw >> 4) & 2047, b = gw >> 15;
  const unsigned short* base = qkv + ((size_t)(b * 2048 + t)) * 3072 + h * 64 + l;
  float qv = bf2f(base[0]);
  float kv = bf2f(base[1024]);
  float sq = qv * qv, sk = kv * kv;
  for (int o = 32; o; o >>= 1) { sq += __shfl_xor(sq, o); sk += __shfl_xor(sk, o); }
  float ssc = sqrtf(scale[h]);
  float fq = ssc * rsqrtf(sq + 1e-6f);
  float fk = ssc * rsqrtf(sk + 1e-6f);
  float qn = qv * fq, kn = kv * fk;
  int e = l;
  int idx24 = (e < 24) ? e : e - 24;
  int partner = (e < 24) ? e + 24 : ((e < 48) ? e - 24 : e);
  float qo = __shfl(qn, partner), ko = __shfl(kn, partner);
  float qr = qn, kr = kn;
  if (e < 48) {
    int a = idx24 >> 3, f = idx24 & 7;
    float th = pos[((size_t)(b * 2048 + t)) * 3 + a] * freqs[h * 8 + f];
    float sn, cs; __sincosf(th, &sn, &cs);
    if (e < 24) { qr = qn * cs - qo * sn; kr = kn * cs - ko * sn; }
    else        { qr = qn * cs + qo * sn; kr = kn * cs + ko * sn; }
  }
  size_t oi = ((size_t)((b * 16 + h) * 2048 + t)) * 64 + e;
  Qo[oi] = f2bf(qr * LOG2E);   // pre-scale: softmax uses exp2
  Ko[oi] = f2bf(kr);
}

// ---------- V transpose: VT[b][h][e][t] ----------
__global__ __launch_bounds__(256) void vtrans_k(const unsigned short* __restrict__ qkv,
                                                unsigned short* __restrict__ VT) {
  __shared__ unsigned short tile[64][72];
  int tt = blockIdx.x, bh = blockIdx.y;
  int b = bh >> 4, h = bh & 15;
  int tid = threadIdx.x;
  for (int ro = 0; ro < 2; ro++) {
    int r = ro * 32 + (tid >> 3);
    int c = (tid & 7) * 8;
    *(bf16x8*)&tile[r][c] =
        *(const bf16x8*)(qkv + ((size_t)(b * 2048 + tt * 64 + r)) * 3072 + 2048 + h * 64 + c);
  }
  __syncthreads();
  int e = tid >> 2;
  int tc = (tid & 3) * 16;
  bf16x8 o0, o1;
  for (int i = 0; i < 8; i++) { o0[i] = (short)tile[tc + i][e]; o1[i] = (short)tile[tc + 8 + i][e]; }
  unsigned short* dst = VT + ((size_t)(bh * 64 + e)) * 2048 + tt * 64 + tc;
  *(bf16x8*)dst = o0;
  *(bf16x8*)(dst + 8) = o1;
}

// ---------- flash attention v4: 32x32 MFMA, in-register softmax, split-K=2 ----------
// grid 1024 = split(2) x bh(32) x qg(16); block 256 = 4 waves; wave = 32 Q-rows.
// Swapped QK^T: S^T = K.Q^T -> lane(q=l&31, hi=l>>5) holds 16 of 32 ktoks per S-tile,
// partner lane (xor 32) the rest. Softmax fully in-register; P->bf16 frags via
// pack + shfl_xor(32). Partial (unnormalized O^T bf16, m/sum f32) to ws; oquant combines.
__global__ __launch_bounds__(256, 3) void attn_k(const unsigned short* __restrict__ Q,
                                                 const unsigned short* __restrict__ K,
                                                 const unsigned short* __restrict__ VT,
                                                 unsigned short* __restrict__ Opart,
                                                 float* __restrict__ ms) {
  __shared__ unsigned short Ks[2][64 * 64];   // [ktok][e], granule ^= (row&7)
  __shared__ unsigned short Vs[2][64 * 64];   // [e][ktok], granule ^= (row&7)
  int tid = threadIdx.x;
  int w = tid >> 6, l = tid & 63;
  int q = l & 31, hi = l >> 5;
  int bx = blockIdx.x;
  int qg = bx & 15;
  int bh = (bx >> 4) & 31;
  int split = bx >> 9;
  int qrow0 = qg * 128 + w * 32;
  const unsigned short* Kbase = K + (size_t)bh * 2048 * 64 + (size_t)split * 1024 * 64;
  const unsigned short* Vbase = VT + (size_t)bh * 64 * 2048 + split * 1024;

  // Q B-frags: lane provides Q[qrow0+q][s*16 + hi*8 + i]
  bf16x8 qa[4];
#pragma unroll
  for (int s = 0; s < 4; s++)
    qa[s] = *(const bf16x8*)(Q + ((size_t)bh * 2048 + qrow0 + q) * 64 + s * 16 + hi * 8);

  // staging lane constants: slots sl = (i*4+w)*64 + l, i=0,1
  int sl0 = (w)*64 + l, sl1 = (4 + w) * 64 + l;
  int r0 = sl0 >> 3, g0 = (sl0 & 7) ^ (r0 & 7);
  int r1 = sl1 >> 3, g1 = (sl1 & 7) ^ (r1 & 7);
  const unsigned short* Kg0 = Kbase + (size_t)r0 * 64 + g0 * 8;
  const unsigned short* Kg1 = Kbase + (size_t)r1 * 64 + g1 * 8;
  const unsigned short* Vg0 = Vbase + (size_t)r0 * 2048 + g0 * 8;
  const unsigned short* Vg1 = Vbase + (size_t)r1 * 2048 + g1 * 8;

  f32x16 acc0 = {0.f}, acc1 = {0.f};
  for (int i = 0; i < 16; i++) { acc0[i] = 0.f; acc1[i] = 0.f; }
  float m = -INFINITY, sum = 0.f;

  auto stage = [&](int buf, int kt) {
    gload_lds16(Kg0 + (size_t)kt * 64, &Ks[buf][w * 512]);
    gload_lds16(Kg1 + (size_t)kt * 64, &Ks[buf][(4 + w) * 512]);
    gload_lds16(Vg0 + kt, &Vs[buf][w * 512]);
    gload_lds16(Vg1 + kt, &Vs[buf][(4 + w) * 512]);
  };

  stage(0, 0);
  __syncthreads();
  int cur = 0;
  for (int it = 0; it < 16; it++) {
    if (it < 15) stage(cur ^ 1, (it + 1) * 64);
    const unsigned short* Ksc = Ks[cur];
    const unsigned short* Vsc = Vs[cur];

    // ---- QK^T: two 32x32 S-tiles (ktoks 0..31, 32..63) ----
    f32x16 s0, s1;
    for (int i = 0; i < 16; i++) { s0[i] = 0.f; s1[i] = 0.f; }
#pragma unroll
    for (int se = 0; se < 4; se++) {
      int gk = (se * 2 + hi);
      bf16x8 ka0 = *(const bf16x8*)&Ksc[(q) * 64 + ((gk ^ (q & 7)) * 8)];
      bf16x8 ka1 = *(const bf16x8*)&Ksc[(32 + q) * 64 + ((gk ^ ((32 + q) & 7)) * 8)];
      s0 = __builtin_amdgcn_mfma_f32_32x32x16_bf16(ka0, qa[se], s0, 0, 0, 0);
      s1 = __builtin_amdgcn_mfma_f32_32x32x16_bf16(ka1, qa[se], s1, 0, 0, 0);
    }

    // ---- in-register online softmax (log2 domain, defer-max THR=8) ----
    float tm = s0[0];
#pragma unroll
    for (int i = 1; i < 16; i++) tm = fmaxf(tm, s0[i]);
#pragma unroll
    for (int i = 0; i < 16; i++) tm = fmaxf(tm, s1[i]);
    tm = fmaxf(tm, __shfl_xor(tm, 32));
    if (!__all(tm - m <= 8.f)) {
      float mn = fmaxf(m, tm);
      float alpha = exp2f(m - mn);
      sum *= alpha;
#pragma unroll
      for (int i = 0; i < 16; i++) { acc0[i] *= alpha; acc1[i] *= alpha; }
      m = mn;
    }
    float p0[16], p1[16], ts = 0.f;
#pragma unroll
    for (int i = 0; i < 16; i++) {
      p0[i] = exp2f(s0[i] - m); p1[i] = exp2f(s1[i] - m);
      ts += p0[i] + p1[i];
    }
    ts += __shfl_xor(ts, 32);
    sum += ts;

    // ---- P -> bf16 B-frags via pack + cross-half exchange ----
    // own ktoks (within 32-tile): reg 0-3 -> 4hi+0..3; 4-7 -> 4hi+8..11;
    // 8-11 -> 4hi+16..19; 12-15 -> 4hi+24..27
    bf16x8 pf[2][2];
#pragma unroll
    for (int ks = 0; ks < 2; ks++) {
      float* p = ks ? p1 : p0;
      unsigned pk[8];
#pragma unroll
      for (int i = 0; i < 8; i++)
        pk[i] = (unsigned)f2bf_hw(p[2 * i]) | ((unsigned)f2bf_hw(p[2 * i + 1]) << 16);
      unsigned xA = __shfl_xor((int)pk[0], 32), xB = __shfl_xor((int)pk[1], 32);
      unsigned xC = __shfl_xor((int)pk[2], 32), xD = __shfl_xor((int)pk[3], 32);
      unsigned xE = __shfl_xor((int)pk[4], 32), xF = __shfl_xor((int)pk[5], 32);
      unsigned xG = __shfl_xor((int)pk[6], 32), xH = __shfl_xor((int)pk[7], 32);
      i32x4 f0, f1;
      f0[0] = hi ? (int)xC : (int)pk[0];
      f0[1] = hi ? (int)xD : (int)pk[1];
      f0[2] = hi ? (int)pk[2] : (int)xA;
      f0[3] = hi ? (int)pk[3] : (int)xB;
      f1[0] = hi ? (int)xG : (int)pk[4];
      f1[1] = hi ? (int)xH : (int)pk[5];
      f1[2] = hi ? (int)pk[6] : (int)xE;
      f1[3] = hi ? (int)pk[7] : (int)xF;
      pf[ks][0] = *(bf16x8*)&f0;
      pf[ks][1] = *(bf16x8*)&f1;
    }

    // ---- PV: O^T[e][q] += V^T . P^T  (2 e-tiles x 2 ks x 2 j) ----
#pragma unroll
    for (int ks = 0; ks < 2; ks++) {
#pragma unroll
      for (int j = 0; j < 2; j++) {
        int gk = ks * 4 + j * 2 + hi;
        bf16x8 va0 = *(const bf16x8*)&Vsc[(q) * 64 + ((gk ^ (q & 7)) * 8)];
        bf16x8 va1 = *(const bf16x8*)&Vsc[(32 + q) * 64 + ((gk ^ ((32 + q) & 7)) * 8)];
        acc0 = __builtin_amdgcn_mfma_f32_32x32x16_bf16(va0, pf[ks][j], acc0, 0, 0, 0);
        acc1 = __builtin_amdgcn_mfma_f32_32x32x16_bf16(va1, pf[ks][j], acc1, 0, 0, 0);
      }
    }
    __syncthreads();     // drains prefetch vmcnt; buffer swap safe
    cur ^= 1;
  }

  // ---- epilogue: unnormalized partial O^T (bf16) + m/sum (f32) ----
  size_t prow = (size_t)(split * 32 + bh) * 2048 + qrow0 + q;
  unsigned short* Op = Opart + prow * 64;
#pragma unroll
  for (int et = 0; et < 2; et++) {
    const f32x16& a = et ? acc1 : acc0;
#pragma unroll
    for (int qd = 0; qd < 4; qd++) {
      int e0 = et * 32 + 4 * hi + qd * 8;
      bf16x4 u;
#pragma unroll
      for (int i = 0; i < 4; i++) u[i] = (short)f2bf_hw(a[qd * 4 + i]);
      *(bf16x4*)&Op[e0] = u;
    }
  }
  if (hi == 0) {
    ms[prow * 2] = m;
    ms[prow * 2 + 1] = sum;
  }
}

extern "C" void kernel_launch(void* const* d_in, const int* in_sizes, int n_in,
                              void* d_out, int out_size, void* d_ws, size_t ws_size,
                              hipStream_t stream) {
  const float* x      = (const float*)d_in[0];
  const float* pos    = (const float*)d_in[1];
  const float* cond   = (const float*)d_in[2];
  const float* norm_w = (const float*)d_in[3];
  const float* qkv_w  = (const float*)d_in[4];
  const float* out_w  = (const float*)d_in[5];
  const float* scale  = (const float*)d_in[6];
  const float* freqs  = (const float*)d_in[7];
  float* out = (float*)d_out;
  char* ws = (char*)d_ws;

  const size_t o_ada    = 0;
  const size_t o_rowsum = 8192;
  const size_t o_scales = 24576;
  const size_t o_Wq     = 24832;
  const size_t o_Wo     = o_Wq + 3072ull*1024*2;
  const size_t o_Aq     = o_Wo + 1024ull*1024*2;
  const size_t o_qkv    = o_Aq + 4096ull*1024*2;     // 24 MB region
  const size_t o_K      = o_qkv + 4096ull*3072*2;
  const size_t o_VT     = o_K + 2ull*16*2048*64*2;

  float* ada            = (float*)(ws + o_ada);
  float* rowsum         = (float*)(ws + o_rowsum);
  float* scales         = (float*)(ws + o_scales);
  unsigned short* Wq    = (unsigned short*)(ws + o_Wq);
  unsigned short* Wo    = (unsigned short*)(ws + o_Wo);
  unsigned short* Aq    = (unsigned short*)(ws + o_Aq);
  unsigned short* Qb    = Aq;                        // reuse after GEMM1
  unsigned short* qkv   = (unsigned short*)(ws + o_qkv);
  // attn partials reuse the qkv region (qkv consumed by rope/vtrans before attn):
  unsigned short* Opart = (unsigned short*)(ws + o_qkv);          // 16.78 MB
  float* msb            = (float*)(ws + o_qkv + 2ull*32*2048*64*2); // 2.1 MB
  unsigned short* Kb    = (unsigned short*)(ws + o_K);
  unsigned short* Oq    = Kb;                        // reuse after attention
  unsigned short* VT    = (unsigned short*)(ws + o_VT);

  wred_k<<<4096, 256, 0, stream>>>(qkv_w, out_w, rowsum);
  finalize_k<<<1, 256, 0, stream>>>(rowsum, scales);
  wquant_k<<<4096, 256, 0, stream>>>(qkv_w, out_w, scales, Wq, Wo);
  ada_k<<<dim3(256, 2), 256, 0, stream>>>(cond, norm_w, ada);
  rmsq_k<<<4096, 256, 0, stream>>>(x, ada, Aq);
  gemm_bt<<<dim3(32, 24), 256, 0, stream>>>(Aq, Wq, 3072, 1024, 0, nullptr, nullptr, qkv);
  rope_k<<<16384, 256, 0, stream>>>(qkv, pos, scale, freqs, Qb, Kb);
  vtrans_k<<<dim3(32, 32), 256, 0, stream>>>(qkv, VT);
  attn_k<<<1024, 256, 0, stream>>>(Qb, Kb, VT, Opart, msb);
  oquant_k<<<4096, 256, 0, stream>>>(Opart, msb, Oq);
  gemm_bt<<<dim3(32, 8), 256, 0, stream>>>(Oq, Wo, 1024, 1024, 1, x, out, nullptr);
}

// Round 7
// 186.187 us; speedup vs baseline: 1.8782x; 1.0146x over previous
//
#include <hip/hip_runtime.h>
#include <hip/hip_bf16.h>
#include <math.h>

typedef __attribute__((ext_vector_type(8))) short bf16x8;
typedef __attribute__((ext_vector_type(4))) short bf16x4;
typedef __attribute__((ext_vector_type(4))) float f32x4;
typedef __attribute__((ext_vector_type(16))) float f32x16;

#define DEV static __device__ __forceinline__
#define LOG2E 1.4426950408889634f

DEV unsigned short f2bf(float f) {
  unsigned int u = __float_as_uint(f);
  u += 0x7FFFu + ((u >> 16) & 1u);   // RNE, inputs finite
  return (unsigned short)(u >> 16);
}
DEV float bf2f(unsigned short h) { return __uint_as_float(((unsigned int)h) << 16); }
DEV float wsum(float v) { for (int o = 32; o; o >>= 1) v += __shfl_xor(v, o); return v; }
DEV float wmaxr(float v) { for (int o = 32; o; o >>= 1) v = fmaxf(v, __shfl_xor(v, o)); return v; }

// async global->LDS, 16B per lane; dest = wave-uniform base + lane*16
DEV void gload_lds16(const void* g, void* s) {
  __builtin_amdgcn_global_load_lds(
      (const __attribute__((address_space(1))) unsigned int*)g,
      (__attribute__((address_space(3))) unsigned int*)s, 16, 0, 0);
}

// ---------- weight-quant scale: per-row |w| sums ----------
__global__ __launch_bounds__(256) void wred_k(const float* __restrict__ qw,
                                              const float* __restrict__ ow,
                                              float* __restrict__ rowsum) {
  int row = blockIdx.x;  // 0..3071 -> qkv_w, 3072..4095 -> out_w
  const float* p = (row < 3072) ? (qw + (size_t)row * 1024)
                                : (ow + (size_t)(row - 3072) * 1024);
  f32x4 v = *(const f32x4*)&p[threadIdx.x * 4];
  float s = fabsf(v[0]) + fabsf(v[1]) + fabsf(v[2]) + fabsf(v[3]);
  s = wsum(s);
  __shared__ float sh[4];
  if ((threadIdx.x & 63) == 0) sh[threadIdx.x >> 6] = s;
  __syncthreads();
  if (threadIdx.x == 0) rowsum[row] = sh[0] + sh[1] + sh[2] + sh[3];
}

__global__ __launch_bounds__(256) void finalize_k(const float* __restrict__ rowsum,
                                                  float* __restrict__ scales) {
  float s1 = 0.f, s2 = 0.f;
  for (int i = threadIdx.x; i < 3072; i += 256) s1 += rowsum[i];
  for (int i = threadIdx.x; i < 1024; i += 256) s2 += rowsum[3072 + i];
  s1 = wsum(s1); s2 = wsum(s2);
  __shared__ float sh1[4], sh2[4];
  if ((threadIdx.x & 63) == 0) { sh1[threadIdx.x >> 6] = s1; sh2[threadIdx.x >> 6] = s2; }
  __syncthreads();
  if (threadIdx.x == 0) {
    float m1 = fmaxf((sh1[0] + sh1[1] + sh1[2] + sh1[3]) / (3072.f * 1024.f), 1e-5f);
    float m2 = fmaxf((sh2[0] + sh2[1] + sh2[2] + sh2[3]) / (1024.f * 1024.f), 1e-5f);
    scales[0] = m1; scales[1] = 1.f / m1;
    scales[2] = m2; scales[3] = 1.f / m2;
  }
}

// ternary-quantize both weight matrices -> bf16 (4.19M elems = 4096*256*4)
__global__ __launch_bounds__(256) void wquant_k(const float* __restrict__ qw,
                                                const float* __restrict__ ow,
                                                const float* __restrict__ scales,
                                                unsigned short* __restrict__ Wq,
                                                unsigned short* __restrict__ Wo) {
  int i0 = (blockIdx.x * 256 + threadIdx.x) * 4;
  if (i0 < 3072 * 1024) {
    f32x4 v = *(const f32x4*)&qw[i0];
    bf16x4 u;
    for (int j = 0; j < 4; j++)
      u[j] = (short)f2bf(fminf(fmaxf(rintf(v[j] * scales[1]), -1.f), 1.f) * scales[0]);
    *(bf16x4*)&Wq[i0] = u;
  } else {
    int k = i0 - 3072 * 1024;
    f32x4 v = *(const f32x4*)&ow[k];
    bf16x4 u;
    for (int j = 0; j < 4; j++)
      u[j] = (short)f2bf(fminf(fmaxf(rintf(v[j] * scales[3]), -1.f), 1.f) * scales[2]);
    *(bf16x4*)&Wo[k] = u;
  }
}

// ---------- ada = 1 + cond @ norm_w^T ----------
__global__ __launch_bounds__(256) void ada_k(const float* __restrict__ cond,
                                             const float* __restrict__ nw,
                                             float* __restrict__ ada) {
  int j = blockIdx.x * 4 + (threadIdx.x >> 6);
  int b = blockIdx.y;
  int l = threadIdx.x & 63;
  const float* cp = cond + b * 1024;
  const float* wp = nw + (size_t)j * 1024;
  float s = 0.f;
  for (int c = l; c < 1024; c += 64) s += cp[c] * wp[c];
  s = wsum(s);
  if (l == 0) ada[b * 1024 + j] = 1.f + s;
}

// ---------- RMSNorm(ada) + act_quant -> bf16 ----------
__global__ __launch_bounds__(256) void rmsq_k(const float* __restrict__ x,
                                              const float* __restrict__ ada,
                                              unsigned short* __restrict__ Aq) {
  int row = blockIdx.x;          // b*2048 + t
  int b = row >> 11;
  const float* xr = x + (size_t)row * 1024;
  const float* ar = ada + b * 1024;
  int t4 = threadIdx.x * 4;
  f32x4 v = *(const f32x4*)&xr[t4];
  float ss = v[0]*v[0] + v[1]*v[1] + v[2]*v[2] + v[3]*v[3];
  ss = wsum(ss);
  __shared__ float sh[4], sh2[4];
  if ((threadIdx.x & 63) == 0) sh[threadIdx.x >> 6] = ss;
  __syncthreads();
  float inv = rsqrtf((sh[0] + sh[1] + sh[2] + sh[3]) * (1.f / 1024.f) + 1e-6f);
  f32x4 a = *(const f32x4*)&ar[t4];
  float xn[4]; float mx = 0.f;
  for (int i = 0; i < 4; i++) { xn[i] = v[i] * a[i] * inv; mx = fmaxf(mx, fabsf(xn[i])); }
  mx = wmaxr(mx);
  if ((threadIdx.x & 63) == 0) sh2[threadIdx.x >> 6] = mx;
  __syncthreads();
  float rmax = fmaxf(fmaxf(sh2[0], sh2[1]), fmaxf(sh2[2], sh2[3]));
  float s = 127.f / fmaxf(rmax, 1e-5f);
  float is = 1.f / s;
  bf16x4 u;
  for (int i = 0; i < 4; i++)
    u[i] = (short)f2bf(fminf(fmaxf(rintf(xn[i] * s), -128.f), 127.f) * is);
  *(bf16x4*)&Aq[(size_t)row * 1024 + t4] = u;
}

// ---------- combine split-K partials + act_quant ----------
__global__ __launch_bounds__(256) void oquant_k(const unsigned short* __restrict__ Opart,
                                                const float* __restrict__ ms,
                                                unsigned short* __restrict__ Oq) {
  int row = blockIdx.x;            // b*2048 + t
  int b = row >> 11, qrow = row & 2047;
  int t4 = threadIdx.x * 4;
  int h = t4 >> 6, e0 = t4 & 63;
  int bh = b * 16 + h;
  size_t i0 = (size_t)bh * 2048 + qrow;             // split 0
  size_t i1 = (size_t)(32 + bh) * 2048 + qrow;      // split 1
  float m0 = ms[i0 * 2], s0 = ms[i0 * 2 + 1];
  float m1 = ms[i1 * 2], s1 = ms[i1 * 2 + 1];
  float mm = fmaxf(m0, m1);
  float a0 = exp2f(m0 - mm), a1 = exp2f(m1 - mm);
  float den = s0 * a0 + s1 * a1;
  float w0 = a0 / den, w1 = a1 / den;
  bf16x4 o0 = *(const bf16x4*)&Opart[i0 * 64 + e0];
  bf16x4 o1 = *(const bf16x4*)&Opart[i1 * 64 + e0];
  float v[4]; float mx = 0.f;
  for (int i = 0; i < 4; i++) {
    v[i] = bf2f((unsigned short)o0[i]) * w0 + bf2f((unsigned short)o1[i]) * w1;
    mx = fmaxf(mx, fabsf(v[i]));
  }
  mx = wmaxr(mx);
  __shared__ float sh[4];
  if ((threadIdx.x & 63) == 0) sh[threadIdx.x >> 6] = mx;
  __syncthreads();
  float rmax = fmaxf(fmaxf(sh[0], sh[1]), fmaxf(sh[2], sh[3]));
  float s = 127.f / fmaxf(rmax, 1e-5f);
  float is = 1.f / s;
  bf16x4 u;
  for (int i = 0; i < 4; i++)
    u[i] = (short)f2bf(fminf(fmaxf(rintf(v[i] * s), -128.f), 127.f) * is);
  *(bf16x4*)&Oq[(size_t)row * 1024 + t4] = u;
}

// ---------- C[M][N] = A[M][K] * B[N][K]^T, 128x128 tile, BK=64, gl_lds + XOR swizzle ----------
__global__ __launch_bounds__(256, 2) void gemm_bt(const unsigned short* __restrict__ A,
                                                  const unsigned short* __restrict__ Bw,
                                                  int N, int K, int mode,
                                                  const float* __restrict__ skip,
                                                  float* __restrict__ outF,
                                                  unsigned short* __restrict__ outB) {
  __shared__ unsigned short As[128 * 64];
  __shared__ unsigned short Bs[128 * 64];
  int tid = threadIdx.x;
  int w = tid >> 6, l = tid & 63;
  int q = l & 15, g = l >> 4;
  int tm = blockIdx.x * 128, tn = blockIdx.y * 128;
  int wr = w >> 1, wc = w & 1;          // wave's 64x64 quadrant
  f32x4 zero = {0.f, 0.f, 0.f, 0.f};
  f32x4 acc[4][4];
#pragma unroll
  for (int m = 0; m < 4; m++)
#pragma unroll
    for (int n = 0; n < 4; n++) acc[m][n] = zero;
  int srow = l >> 3;
  int sg = (l & 7) ^ srow;              // inverse-swizzled source granule
  const unsigned short* Ag = A + (size_t)(tm + srow) * K + sg * 8;
  const unsigned short* Bg = Bw + (size_t)(tn + srow) * K + sg * 8;
  for (int k0 = 0; k0 < K; k0 += 64) {
#pragma unroll
    for (int ra = 0; ra < 4; ra++) {
      size_t roff = (size_t)((w * 4 + ra) * 8) * K + k0;
      gload_lds16(Ag + roff, &As[(w * 4 + ra) * 512]);
      gload_lds16(Bg + roff, &Bs[(w * 4 + ra) * 512]);
    }
    __syncthreads();
#pragma unroll
    for (int kk = 0; kk < 2; kk++) {
      int gs = ((kk * 4 + g) ^ (q & 7)) * 8;
      bf16x8 af[4], bfr[4];
#pragma unroll
      for (int m = 0; m < 4; m++)
        af[m] = *(const bf16x8*)&As[(wr * 64 + m * 16 + q) * 64 + gs];
#pragma unroll
      for (int n = 0; n < 4; n++)
        bfr[n] = *(const bf16x8*)&Bs[(wc * 64 + n * 16 + q) * 64 + gs];
#pragma unroll
      for (int m = 0; m < 4; m++)
#pragma unroll
        for (int n = 0; n < 4; n++)
          acc[m][n] = __builtin_amdgcn_mfma_f32_16x16x32_bf16(af[m], bfr[n], acc[m][n], 0, 0, 0);
    }
    __syncthreads();
  }
#pragma unroll
  for (int m = 0; m < 4; m++) {
#pragma unroll
    for (int n = 0; n < 4; n++) {
      int col = tn + wc * 64 + n * 16 + q;
#pragma unroll
      for (int r = 0; r < 4; r++) {
        int row = tm + wr * 64 + m * 16 + g * 4 + r;
        float vv = acc[m][n][r];
        if (mode == 0) outB[(size_t)row * N + col] = f2bf(vv);
        else { size_t idx = (size_t)row * N + col; outF[idx] = vv + skip[idx]; }
      }
    }
  }
}

// ---------- qk-norm + RoPE (Q pre-scaled by log2(e) for exp2-softmax) ----------
__global__ __launch_bounds__(256) void rope_k(const unsigned short* __restrict__ qkv,
                                              const float* __restrict__ pos,
                                              const float* __restrict__ scale,
                                              const float* __restrict__ freqs,
                                              unsigned short* __restrict__ Qo,
                                              unsigned short* __restrict__ Ko) {
  int tid = threadIdx.x;
  int w = tid >> 6, l = tid & 63;
  int gw = blockIdx.x * 4 + w;            // b*32768 + t*16 + h
  int h = gw & 15, t = (gw >> 4) & 2047, b = gw >> 15;
  const unsigned short* base = qkv + ((size_t)(b * 2048 + t)) * 3072 + h * 64 + l;
  float qv = bf2f(base[0]);
  float kv = bf2f(base[1024]);
  float sq = qv * qv, sk = kv * kv;
  for (int o = 32; o; o >>= 1) { sq += __shfl_xor(sq, o); sk += __shfl_xor(sk, o); }
  float ssc = sqrtf(scale[h]);
  float fq = ssc * rsqrtf(sq + 1e-6f);
  float fk = ssc * rsqrtf(sk + 1e-6f);
  float qn = qv * fq, kn = kv * fk;
  int e = l;
  int idx24 = (e < 24) ? e : e - 24;
  int partner = (e < 24) ? e + 24 : ((e < 48) ? e - 24 : e);
  float qo = __shfl(qn, partner), ko = __shfl(kn, partner);
  float qr = qn, kr = kn;
  if (e < 48) {
    int a = idx24 >> 3, f = idx24 & 7;
    float th = pos[((size_t)(b * 2048 + t)) * 3 + a] * freqs[h * 8 + f];
    float sn, cs; __sincosf(th, &sn, &cs);
    if (e < 24) { qr = qn * cs - qo * sn; kr = kn * cs - ko * sn; }
    else        { qr = qn * cs + qo * sn; kr = kn * cs + ko * sn; }
  }
  size_t oi = ((size_t)((b * 16 + h) * 2048 + t)) * 64 + e;
  Qo[oi] = f2bf(qr * LOG2E);   // pre-scale: softmax uses exp2
  Ko[oi] = f2bf(kr);
}

// ---------- V transpose: VT[b][h][e][t'], t' = t with bits2<->3 swapped in 16-blk ----------
// The swap bakes the PV k-permutation into VT so attn needs ZERO cross-lane P exchange
// (S C-layout reg order == PV B-frag order under this permutation).
__global__ __launch_bounds__(256) void vtrans_k(const unsigned short* __restrict__ qkv,
                                                unsigned short* __restrict__ VT) {
  __shared__ unsigned short tile[64][72];
  int tt = blockIdx.x, bh = blockIdx.y;
  int b = bh >> 4, h = bh & 15;
  int tid = threadIdx.x;
  for (int ro = 0; ro < 2; ro++) {
    int r = ro * 32 + (tid >> 3);
    int c = (tid & 7) * 8;
    *(bf16x8*)&tile[r][c] =
        *(const bf16x8*)(qkv + ((size_t)(b * 2048 + tt * 64 + r)) * 3072 + 2048 + h * 64 + c);
  }
  __syncthreads();
  int e = tid >> 2;
  int tc = (tid & 3) * 16;
  bf16x8 o0, o1;
#pragma unroll
  for (int i = 0; i < 4; i++) {
    o0[i]     = (short)tile[tc + i][e];        // dst 0..3   <- tok 0..3
    o0[4 + i] = (short)tile[tc + 8 + i][e];    // dst 4..7   <- tok 8..11
    o1[i]     = (short)tile[tc + 4 + i][e];    // dst 8..11  <- tok 4..7
    o1[4 + i] = (short)tile[tc + 12 + i][e];   // dst 12..15 <- tok 12..15
  }
  unsigned short* dst = VT + ((size_t)(bh * 64 + e)) * 2048 + tt * 64 + tc;
  *(bf16x8*)dst = o0;
  *(bf16x8*)(dst + 8) = o1;
}

// ---------- flash attention v5: 32x32 MFMA, zero-shuffle PV, split-K=2 ----------
// grid 1024 = split(2) x bh(32) x qg(16); block 256 = 4 waves; wave = 32 Q-rows.
// Swapped QK^T (S^T = K.Q^T): lane (q=l&31, hi=l>>5) holds S C-layout regs for its q.
// V columns pre-permuted (vtrans_k) so pf[n] = pack of own regs — no shuffles.
__global__ __launch_bounds__(256, 3) void attn_k(const unsigned short* __restrict__ Q,
                                                 const unsigned short* __restrict__ K,
                                                 const unsigned short* __restrict__ VT,
                                                 unsigned short* __restrict__ Opart,
                                                 float* __restrict__ ms) {
  __shared__ unsigned short Ks[2][64 * 64];   // [ktok][e], granule ^= (row&7)
  __shared__ unsigned short Vs[2][64 * 64];   // [e][ktok'], granule ^= (row&7)
  int tid = threadIdx.x;
  int w = tid >> 6, l = tid & 63;
  int q = l & 31, hi = l >> 5;
  int bx = blockIdx.x;
  int qg = bx & 15;
  int bh = (bx >> 4) & 31;
  int split = bx >> 9;
  int qrow0 = qg * 128 + w * 32;
  const unsigned short* Kbase = K + (size_t)bh * 2048 * 64 + (size_t)split * 1024 * 64;
  const unsigned short* Vbase = VT + (size_t)bh * 64 * 2048 + split * 1024;

  // Q B-frags: lane provides Q[qrow0+q][s*16 + hi*8 + j]
  bf16x8 qa[4];
#pragma unroll
  for (int s = 0; s < 4; s++)
    qa[s] = *(const bf16x8*)(Q + ((size_t)bh * 2048 + qrow0 + q) * 64 + s * 16 + hi * 8);

  // loop-invariant LDS read offsets; identical formula for K (QK^T) and V (PV)
  int off0[4], off1[4];
#pragma unroll
  for (int se = 0; se < 4; se++) {
    int gk = se * 2 + hi;
    off0[se] = q * 64 + ((gk ^ (q & 7)) * 8);
    off1[se] = (32 + q) * 64 + ((gk ^ (q & 7)) * 8);
  }

  // staging lane constants: slots sl = (i*4+w)*64 + l, i=0,1
  int sl0 = (w)*64 + l, sl1 = (4 + w) * 64 + l;
  int r0 = sl0 >> 3, g0 = (sl0 & 7) ^ (r0 & 7);
  int r1 = sl1 >> 3, g1 = (sl1 & 7) ^ (r1 & 7);
  const unsigned short* Kg0 = Kbase + (size_t)r0 * 64 + g0 * 8;
  const unsigned short* Kg1 = Kbase + (size_t)r1 * 64 + g1 * 8;
  const unsigned short* Vg0 = Vbase + (size_t)r0 * 2048 + g0 * 8;
  const unsigned short* Vg1 = Vbase + (size_t)r1 * 2048 + g1 * 8;

  f32x16 acc0, acc1;
  for (int i = 0; i < 16; i++) { acc0[i] = 0.f; acc1[i] = 0.f; }
  float m = -INFINITY, sum = 0.f;

  auto stage = [&](int buf, int kt) {
    gload_lds16(Kg0 + (size_t)kt * 64, &Ks[buf][w * 512]);
    gload_lds16(Kg1 + (size_t)kt * 64, &Ks[buf][(4 + w) * 512]);
    gload_lds16(Vg0 + kt, &Vs[buf][w * 512]);
    gload_lds16(Vg1 + kt, &Vs[buf][(4 + w) * 512]);
  };

  stage(0, 0);
  __syncthreads();
  int cur = 0;
  for (int it = 0; it < 16; it++) {
    if (it < 15) stage(cur ^ 1, (it + 1) * 64);
    const unsigned short* Ksc = Ks[cur];
    const unsigned short* Vsc = Vs[cur];

    // ---- QK^T: two 32x32 S-tiles (ktoks 0..31, 32..63) ----
    f32x16 s0, s1;
    for (int i = 0; i < 16; i++) { s0[i] = 0.f; s1[i] = 0.f; }
    __builtin_amdgcn_s_setprio(1);
#pragma unroll
    for (int se = 0; se < 4; se++) {
      bf16x8 ka0 = *(const bf16x8*)&Ksc[off0[se]];
      bf16x8 ka1 = *(const bf16x8*)&Ksc[off1[se]];
      s0 = __builtin_amdgcn_mfma_f32_32x32x16_bf16(ka0, qa[se], s0, 0, 0, 0);
      s1 = __builtin_amdgcn_mfma_f32_32x32x16_bf16(ka1, qa[se], s1, 0, 0, 0);
    }
    __builtin_amdgcn_s_setprio(0);

    // ---- in-register online softmax (log2 domain, defer-max THR=8) ----
    float tm = s0[0];
#pragma unroll
    for (int i = 1; i < 16; i++) tm = fmaxf(tm, s0[i]);
#pragma unroll
    for (int i = 0; i < 16; i++) tm = fmaxf(tm, s1[i]);
    tm = fmaxf(tm, __shfl_xor(tm, 32));
    if (!__all(tm - m <= 8.f)) {
      float mn = fmaxf(m, tm);
      float alpha = exp2f(m - mn);
      sum *= alpha;
#pragma unroll
      for (int i = 0; i < 16; i++) { acc0[i] *= alpha; acc1[i] *= alpha; }
      m = mn;
    }
    float p0[16], p1[16], ts = 0.f;
#pragma unroll
    for (int i = 0; i < 16; i++) {
      p0[i] = exp2f(s0[i] - m); p1[i] = exp2f(s1[i] - m);
      ts += p0[i] + p1[i];
    }
    ts += __shfl_xor(ts, 32);
    sum += ts;

    // ---- P B-frags = own regs, packed in order (V pre-permuted) ----
    bf16x8 pf[4];
#pragma unroll
    for (int n = 0; n < 4; n++) {
      const float* p = (n < 2) ? p0 : p1;
      int o = (n & 1) * 8;
      bf16x8 u;
#pragma unroll
      for (int j = 0; j < 8; j++) u[j] = (short)f2bf(p[o + j]);
      pf[n] = u;
    }

    // ---- PV: O^T += V^T . P^T ----
    __builtin_amdgcn_s_setprio(1);
#pragma unroll
    for (int n = 0; n < 4; n++) {
      bf16x8 va0 = *(const bf16x8*)&Vsc[off0[n]];
      bf16x8 va1 = *(const bf16x8*)&Vsc[off1[n]];
      acc0 = __builtin_amdgcn_mfma_f32_32x32x16_bf16(va0, pf[n], acc0, 0, 0, 0);
      acc1 = __builtin_amdgcn_mfma_f32_32x32x16_bf16(va1, pf[n], acc1, 0, 0, 0);
    }
    __builtin_amdgcn_s_setprio(0);
    __syncthreads();     // drains prefetch vmcnt; buffer swap safe
    cur ^= 1;
  }

  // ---- epilogue: unnormalized partial O^T (bf16) + m/sum (f32) ----
  size_t prow = (size_t)(split * 32 + bh) * 2048 + qrow0 + q;
  unsigned short* Op = Opart + prow * 64;
#pragma unroll
  for (int et = 0; et < 2; et++) {
    const f32x16& a = et ? acc1 : acc0;
#pragma unroll
    for (int qd = 0; qd < 4; qd++) {
      int e0 = et * 32 + 4 * hi + qd * 8;
      bf16x4 u;
#pragma unroll
      for (int i = 0; i < 4; i++) u[i] = (short)f2bf(a[qd * 4 + i]);
      *(bf16x4*)&Op[e0] = u;
    }
  }
  if (hi == 0) {
    ms[prow * 2] = m;
    ms[prow * 2 + 1] = sum;
  }
}

extern "C" void kernel_launch(void* const* d_in, const int* in_sizes, int n_in,
                              void* d_out, int out_size, void* d_ws, size_t ws_size,
                              hipStream_t stream) {
  const float* x      = (const float*)d_in[0];
  const float* pos    = (const float*)d_in[1];
  const float* cond   = (const float*)d_in[2];
  const float* norm_w = (const float*)d_in[3];
  const float* qkv_w  = (const float*)d_in[4];
  const float* out_w  = (const float*)d_in[5];
  const float* scale  = (const float*)d_in[6];
  const float* freqs  = (const float*)d_in[7];
  float* out = (float*)d_out;
  char* ws = (char*)d_ws;

  const size_t o_ada    = 0;
  const size_t o_rowsum = 8192;
  const size_t o_scales = 24576;
  const size_t o_Wq     = 24832;
  const size_t o_Wo     = o_Wq + 3072ull*1024*2;
  const size_t o_Aq     = o_Wo + 1024ull*1024*2;
  const size_t o_qkv    = o_Aq + 4096ull*1024*2;     // 24 MB region
  const size_t o_K      = o_qkv + 4096ull*3072*2;
  const size_t o_VT     = o_K + 2ull*16*2048*64*2;

  float* ada            = (float*)(ws + o_ada);
  float* rowsum         = (float*)(ws + o_rowsum);
  float* scales         = (float*)(ws + o_scales);
  unsigned short* Wq    = (unsigned short*)(ws + o_Wq);
  unsigned short* Wo    = (unsigned short*)(ws + o_Wo);
  unsigned short* Aq    = (unsigned short*)(ws + o_Aq);
  unsigned short* Qb    = Aq;                        // reuse after GEMM1
  unsigned short* qkv   = (unsigned short*)(ws + o_qkv);
  unsigned short* Opart = (unsigned short*)(ws + o_qkv);            // reuse (16.78 MB)
  float* msb            = (float*)(ws + o_qkv + 2ull*32*2048*64*2); // 2.1 MB
  unsigned short* Kb    = (unsigned short*)(ws + o_K);
  unsigned short* Oq    = Kb;                        // reuse after attention
  unsigned short* VT    = (unsigned short*)(ws + o_VT);

  wred_k<<<4096, 256, 0, stream>>>(qkv_w, out_w, rowsum);
  finalize_k<<<1, 256, 0, stream>>>(rowsum, scales);
  wquant_k<<<4096, 256, 0, stream>>>(qkv_w, out_w, scales, Wq, Wo);
  ada_k<<<dim3(256, 2), 256, 0, stream>>>(cond, norm_w, ada);
  rmsq_k<<<4096, 256, 0, stream>>>(x, ada, Aq);
  gemm_bt<<<dim3(32, 24), 256, 0, stream>>>(Aq, Wq, 3072, 1024, 0, nullptr, nullptr, qkv);
  rope_k<<<16384, 256, 0, stream>>>(qkv, pos, scale, freqs, Qb, Kb);
  vtrans_k<<<dim3(32, 32), 256, 0, stream>>>(qkv, VT);
  attn_k<<<1024, 256, 0, stream>>>(Qb, Kb, VT, Opart, msb);
  oquant_k<<<4096, 256, 0, stream>>>(Opart, msb, Oq);
  gemm_bt<<<dim3(32, 8), 256, 0, stream>>>(Oq, Wo, 1024, 1024, 1, x, out, nullptr);
}

// Round 8
// 180.838 us; speedup vs baseline: 1.9338x; 1.0296x over previous
//
#include <hip/hip_runtime.h>
#include <hip/hip_bf16.h>
#include <math.h>

typedef __attribute__((ext_vector_type(8))) short bf16x8;
typedef __attribute__((ext_vector_type(4))) short bf16x4;
typedef __attribute__((ext_vector_type(4))) float f32x4;
typedef __attribute__((ext_vector_type(16))) float f32x16;
typedef __attribute__((ext_vector_type(4))) unsigned u32x4;
typedef __attribute__((ext_vector_type(2))) unsigned u32x2;

#define DEV static __device__ __forceinline__
#define LOG2E 1.4426950408889634f

DEV unsigned short f2bf(float f) {
  unsigned int u = __float_as_uint(f);
  u += 0x7FFFu + ((u >> 16) & 1u);   // RNE, inputs finite
  return (unsigned short)(u >> 16);
}
DEV float bf2f(unsigned short h) { return __uint_as_float(((unsigned int)h) << 16); }
// packed f32x2 -> bf16x2 (RNE), 1 instr; low word = first arg (T12 recipe)
DEV unsigned cvtpk(float lo, float hi) {
  unsigned r;
  asm("v_cvt_pk_bf16_f32 %0, %1, %2" : "=v"(r) : "v"(lo), "v"(hi));
  return r;
}
DEV float wsum(float v) { for (int o = 32; o; o >>= 1) v += __shfl_xor(v, o); return v; }
DEV float wmaxr(float v) { for (int o = 32; o; o >>= 1) v = fmaxf(v, __shfl_xor(v, o)); return v; }

// async global->LDS, 16B per lane; dest = wave-uniform base + lane*16
DEV void gload_lds16(const void* g, void* s) {
  __builtin_amdgcn_global_load_lds(
      (const __attribute__((address_space(1))) unsigned int*)g,
      (__attribute__((address_space(3))) unsigned int*)s, 16, 0, 0);
}

// ---------- weight-quant scale: per-row |w| sums ----------
__global__ __launch_bounds__(256) void wred_k(const float* __restrict__ qw,
                                              const float* __restrict__ ow,
                                              float* __restrict__ rowsum) {
  int row = blockIdx.x;  // 0..3071 -> qkv_w, 3072..4095 -> out_w
  const float* p = (row < 3072) ? (qw + (size_t)row * 1024)
                                : (ow + (size_t)(row - 3072) * 1024);
  f32x4 v = *(const f32x4*)&p[threadIdx.x * 4];
  float s = fabsf(v[0]) + fabsf(v[1]) + fabsf(v[2]) + fabsf(v[3]);
  s = wsum(s);
  __shared__ float sh[4];
  if ((threadIdx.x & 63) == 0) sh[threadIdx.x >> 6] = s;
  __syncthreads();
  if (threadIdx.x == 0) rowsum[row] = sh[0] + sh[1] + sh[2] + sh[3];
}

__global__ __launch_bounds__(256) void finalize_k(const float* __restrict__ rowsum,
                                                  float* __restrict__ scales) {
  float s1 = 0.f, s2 = 0.f;
  for (int i = threadIdx.x; i < 3072; i += 256) s1 += rowsum[i];
  for (int i = threadIdx.x; i < 1024; i += 256) s2 += rowsum[3072 + i];
  s1 = wsum(s1); s2 = wsum(s2);
  __shared__ float sh1[4], sh2[4];
  if ((threadIdx.x & 63) == 0) { sh1[threadIdx.x >> 6] = s1; sh2[threadIdx.x >> 6] = s2; }
  __syncthreads();
  if (threadIdx.x == 0) {
    float m1 = fmaxf((sh1[0] + sh1[1] + sh1[2] + sh1[3]) / (3072.f * 1024.f), 1e-5f);
    float m2 = fmaxf((sh2[0] + sh2[1] + sh2[2] + sh2[3]) / (1024.f * 1024.f), 1e-5f);
    scales[0] = m1; scales[1] = 1.f / m1;
    scales[2] = m2; scales[3] = 1.f / m2;
  }
}

// ternary-quantize both weight matrices -> bf16 (4.19M elems = 4096*256*4)
__global__ __launch_bounds__(256) void wquant_k(const float* __restrict__ qw,
                                                const float* __restrict__ ow,
                                                const float* __restrict__ scales,
                                                unsigned short* __restrict__ Wq,
                                                unsigned short* __restrict__ Wo) {
  int i0 = (blockIdx.x * 256 + threadIdx.x) * 4;
  if (i0 < 3072 * 1024) {
    f32x4 v = *(const f32x4*)&qw[i0];
    bf16x4 u;
    for (int j = 0; j < 4; j++)
      u[j] = (short)f2bf(fminf(fmaxf(rintf(v[j] * scales[1]), -1.f), 1.f) * scales[0]);
    *(bf16x4*)&Wq[i0] = u;
  } else {
    int k = i0 - 3072 * 1024;
    f32x4 v = *(const f32x4*)&ow[k];
    bf16x4 u;
    for (int j = 0; j < 4; j++)
      u[j] = (short)f2bf(fminf(fmaxf(rintf(v[j] * scales[3]), -1.f), 1.f) * scales[2]);
    *(bf16x4*)&Wo[k] = u;
  }
}

// ---------- ada = 1 + cond @ norm_w^T ----------
__global__ __launch_bounds__(256) void ada_k(const float* __restrict__ cond,
                                             const float* __restrict__ nw,
                                             float* __restrict__ ada) {
  int j = blockIdx.x * 4 + (threadIdx.x >> 6);
  int b = blockIdx.y;
  int l = threadIdx.x & 63;
  const float* cp = cond + b * 1024;
  const float* wp = nw + (size_t)j * 1024;
  float s = 0.f;
  for (int c = l; c < 1024; c += 64) s += cp[c] * wp[c];
  s = wsum(s);
  if (l == 0) ada[b * 1024 + j] = 1.f + s;
}

// ---------- RMSNorm(ada) + act_quant -> bf16 ----------
__global__ __launch_bounds__(256) void rmsq_k(const float* __restrict__ x,
                                              const float* __restrict__ ada,
                                              unsigned short* __restrict__ Aq) {
  int row = blockIdx.x;          // b*2048 + t
  int b = row >> 11;
  const float* xr = x + (size_t)row * 1024;
  const float* ar = ada + b * 1024;
  int t4 = threadIdx.x * 4;
  f32x4 v = *(const f32x4*)&xr[t4];
  float ss = v[0]*v[0] + v[1]*v[1] + v[2]*v[2] + v[3]*v[3];
  ss = wsum(ss);
  __shared__ float sh[4], sh2[4];
  if ((threadIdx.x & 63) == 0) sh[threadIdx.x >> 6] = ss;
  __syncthreads();
  float inv = rsqrtf((sh[0] + sh[1] + sh[2] + sh[3]) * (1.f / 1024.f) + 1e-6f);
  f32x4 a = *(const f32x4*)&ar[t4];
  float xn[4]; float mx = 0.f;
  for (int i = 0; i < 4; i++) { xn[i] = v[i] * a[i] * inv; mx = fmaxf(mx, fabsf(xn[i])); }
  mx = wmaxr(mx);
  if ((threadIdx.x & 63) == 0) sh2[threadIdx.x >> 6] = mx;
  __syncthreads();
  float rmax = fmaxf(fmaxf(sh2[0], sh2[1]), fmaxf(sh2[2], sh2[3]));
  float s = 127.f / fmaxf(rmax, 1e-5f);
  float is = 1.f / s;
  bf16x4 u;
  for (int i = 0; i < 4; i++)
    u[i] = (short)f2bf(fminf(fmaxf(rintf(xn[i] * s), -128.f), 127.f) * is);
  *(bf16x4*)&Aq[(size_t)row * 1024 + t4] = u;
}

// ---------- combine split-K partials + act_quant ----------
__global__ __launch_bounds__(256) void oquant_k(const unsigned short* __restrict__ Opart,
                                                const float* __restrict__ ms,
                                                unsigned short* __restrict__ Oq) {
  int row = blockIdx.x;            // b*2048 + t
  int b = row >> 11, qrow = row & 2047;
  int t4 = threadIdx.x * 4;
  int h = t4 >> 6, e0 = t4 & 63;
  int bh = b * 16 + h;
  size_t i0 = (size_t)bh * 2048 + qrow;             // split 0
  size_t i1 = (size_t)(32 + bh) * 2048 + qrow;      // split 1
  float m0 = ms[i0 * 2], s0 = ms[i0 * 2 + 1];
  float m1 = ms[i1 * 2], s1 = ms[i1 * 2 + 1];
  float mm = fmaxf(m0, m1);
  float a0 = exp2f(m0 - mm), a1 = exp2f(m1 - mm);
  float den = s0 * a0 + s1 * a1;
  float w0 = a0 / den, w1 = a1 / den;
  bf16x4 o0 = *(const bf16x4*)&Opart[i0 * 64 + e0];
  bf16x4 o1 = *(const bf16x4*)&Opart[i1 * 64 + e0];
  float v[4]; float mx = 0.f;
  for (int i = 0; i < 4; i++) {
    v[i] = bf2f((unsigned short)o0[i]) * w0 + bf2f((unsigned short)o1[i]) * w1;
    mx = fmaxf(mx, fabsf(v[i]));
  }
  mx = wmaxr(mx);
  __shared__ float sh[4];
  if ((threadIdx.x & 63) == 0) sh[threadIdx.x >> 6] = mx;
  __syncthreads();
  float rmax = fmaxf(fmaxf(sh[0], sh[1]), fmaxf(sh[2], sh[3]));
  float s = 127.f / fmaxf(rmax, 1e-5f);
  float is = 1.f / s;
  bf16x4 u;
  for (int i = 0; i < 4; i++)
    u[i] = (short)f2bf(fminf(fmaxf(rintf(v[i] * s), -128.f), 127.f) * is);
  *(bf16x4*)&Oq[(size_t)row * 1024 + t4] = u;
}

// ---------- C[M][N] = A[M][K] * B[N][K]^T, 128x128 tile, BK=64, gl_lds + XOR swizzle ----------
__global__ __launch_bounds__(256, 2) void gemm_bt(const unsigned short* __restrict__ A,
                                                  const unsigned short* __restrict__ Bw,
                                                  int N, int K, int mode,
                                                  const float* __restrict__ skip,
                                                  float* __restrict__ outF,
                                                  unsigned short* __restrict__ outB) {
  __shared__ unsigned short As[128 * 64];
  __shared__ unsigned short Bs[128 * 64];
  int tid = threadIdx.x;
  int w = tid >> 6, l = tid & 63;
  int q = l & 15, g = l >> 4;
  int tm = blockIdx.x * 128, tn = blockIdx.y * 128;
  int wr = w >> 1, wc = w & 1;          // wave's 64x64 quadrant
  f32x4 zero = {0.f, 0.f, 0.f, 0.f};
  f32x4 acc[4][4];
#pragma unroll
  for (int m = 0; m < 4; m++)
#pragma unroll
    for (int n = 0; n < 4; n++) acc[m][n] = zero;
  int srow = l >> 3;
  int sg = (l & 7) ^ srow;              // inverse-swizzled source granule
  const unsigned short* Ag = A + (size_t)(tm + srow) * K + sg * 8;
  const unsigned short* Bg = Bw + (size_t)(tn + srow) * K + sg * 8;
  for (int k0 = 0; k0 < K; k0 += 64) {
#pragma unroll
    for (int ra = 0; ra < 4; ra++) {
      size_t roff = (size_t)((w * 4 + ra) * 8) * K + k0;
      gload_lds16(Ag + roff, &As[(w * 4 + ra) * 512]);
      gload_lds16(Bg + roff, &Bs[(w * 4 + ra) * 512]);
    }
    __syncthreads();
#pragma unroll
    for (int kk = 0; kk < 2; kk++) {
      int gs = ((kk * 4 + g) ^ (q & 7)) * 8;
      bf16x8 af[4], bfr[4];
#pragma unroll
      for (int m = 0; m < 4; m++)
        af[m] = *(const bf16x8*)&As[(wr * 64 + m * 16 + q) * 64 + gs];
#pragma unroll
      for (int n = 0; n < 4; n++)
        bfr[n] = *(const bf16x8*)&Bs[(wc * 64 + n * 16 + q) * 64 + gs];
#pragma unroll
      for (int m = 0; m < 4; m++)
#pragma unroll
        for (int n = 0; n < 4; n++)
          acc[m][n] = __builtin_amdgcn_mfma_f32_16x16x32_bf16(af[m], bfr[n], acc[m][n], 0, 0, 0);
    }
    __syncthreads();
  }
#pragma unroll
  for (int m = 0; m < 4; m++) {
#pragma unroll
    for (int n = 0; n < 4; n++) {
      int col = tn + wc * 64 + n * 16 + q;
#pragma unroll
      for (int r = 0; r < 4; r++) {
        int row = tm + wr * 64 + m * 16 + g * 4 + r;
        float vv = acc[m][n][r];
        if (mode == 0) outB[(size_t)row * N + col] = f2bf(vv);
        else { size_t idx = (size_t)row * N + col; outF[idx] = vv + skip[idx]; }
      }
    }
  }
}

// ---------- qk-norm + RoPE (Q pre-scaled by log2(e) for exp2-softmax) ----------
__global__ __launch_bounds__(256) void rope_k(const unsigned short* __restrict__ qkv,
                                              const float* __restrict__ pos,
                                              const float* __restrict__ scale,
                                              const float* __restrict__ freqs,
                                              unsigned short* __restrict__ Qo,
                                              unsigned short* __restrict__ Ko) {
  int tid = threadIdx.x;
  int w = tid >> 6, l = tid & 63;
  int gw = blockIdx.x * 4 + w;            // b*32768 + t*16 + h
  int h = gw & 15, t = (gw >> 4) & 2047, b = gw >> 15;
  const unsigned short* base = qkv + ((size_t)(b * 2048 + t)) * 3072 + h * 64 + l;
  float qv = bf2f(base[0]);
  float kv = bf2f(base[1024]);
  float sq = qv * qv, sk = kv * kv;
  for (int o = 32; o; o >>= 1) { sq += __shfl_xor(sq, o); sk += __shfl_xor(sk, o); }
  float ssc = sqrtf(scale[h]);
  float fq = ssc * rsqrtf(sq + 1e-6f);
  float fk = ssc * rsqrtf(sk + 1e-6f);
  float qn = qv * fq, kn = kv * fk;
  int e = l;
  int idx24 = (e < 24) ? e : e - 24;
  int partner = (e < 24) ? e + 24 : ((e < 48) ? e - 24 : e);
  float qo = __shfl(qn, partner), ko = __shfl(kn, partner);
  float qr = qn, kr = kn;
  if (e < 48) {
    int a = idx24 >> 3, f = idx24 & 7;
    float th = pos[((size_t)(b * 2048 + t)) * 3 + a] * freqs[h * 8 + f];
    float sn, cs; __sincosf(th, &sn, &cs);
    if (e < 24) { qr = qn * cs - qo * sn; kr = kn * cs - ko * sn; }
    else        { qr = qn * cs + qo * sn; kr = kn * cs + ko * sn; }
  }
  size_t oi = ((size_t)((b * 16 + h) * 2048 + t)) * 64 + e;
  Qo[oi] = f2bf(qr * LOG2E);   // pre-scale: softmax uses exp2
  Ko[oi] = f2bf(kr);
}

// ---------- V transpose: VT[b][h][e][t'], t' = t with bits2<->3 swapped in 16-blk ----------
// The swap bakes the PV k-permutation into VT so attn needs ZERO cross-lane P exchange
// (S C-layout reg order == PV B-frag order under this permutation).
__global__ __launch_bounds__(256) void vtrans_k(const unsigned short* __restrict__ qkv,
                                                unsigned short* __restrict__ VT) {
  __shared__ unsigned short tile[64][72];
  int tt = blockIdx.x, bh = blockIdx.y;
  int b = bh >> 4, h = bh & 15;
  int tid = threadIdx.x;
  for (int ro = 0; ro < 2; ro++) {
    int r = ro * 32 + (tid >> 3);
    int c = (tid & 7) * 8;
    *(bf16x8*)&tile[r][c] =
        *(const bf16x8*)(qkv + ((size_t)(b * 2048 + tt * 64 + r)) * 3072 + 2048 + h * 64 + c);
  }
  __syncthreads();
  int e = tid >> 2;
  int tc = (tid & 3) * 16;
  bf16x8 o0, o1;
#pragma unroll
  for (int i = 0; i < 4; i++) {
    o0[i]     = (short)tile[tc + i][e];        // dst 0..3   <- tok 0..3
    o0[4 + i] = (short)tile[tc + 8 + i][e];    // dst 4..7   <- tok 8..11
    o1[i]     = (short)tile[tc + 4 + i][e];    // dst 8..11  <- tok 4..7
    o1[4 + i] = (short)tile[tc + 12 + i][e];   // dst 12..15 <- tok 12..15
  }
  unsigned short* dst = VT + ((size_t)(bh * 64 + e)) * 2048 + tt * 64 + tc;
  *(bf16x8*)dst = o0;
  *(bf16x8*)(dst + 8) = o1;
}

// ---------- flash attention v6: 32x32 MFMA, zero-shuffle PV, cvt_pk softmax ----------
// grid 1024 = split(2) x bh(32) x qg(16); block 256 = 4 waves; wave = 32 Q-rows.
__global__ __launch_bounds__(256, 3) void attn_k(const unsigned short* __restrict__ Q,
                                                 const unsigned short* __restrict__ K,
                                                 const unsigned short* __restrict__ VT,
                                                 unsigned short* __restrict__ Opart,
                                                 float* __restrict__ ms) {
  __shared__ unsigned short Ks[2][64 * 64];   // [ktok][e], granule ^= (row&7)
  __shared__ unsigned short Vs[2][64 * 64];   // [e][ktok'], granule ^= (row&7)
  int tid = threadIdx.x;
  int w = tid >> 6, l = tid & 63;
  int q = l & 31, hi = l >> 5;
  int bx = blockIdx.x;
  int qg = bx & 15;
  int bh = (bx >> 4) & 31;
  int split = bx >> 9;
  int qrow0 = qg * 128 + w * 32;
  const unsigned short* Kbase = K + (size_t)bh * 2048 * 64 + (size_t)split * 1024 * 64;
  const unsigned short* Vbase = VT + (size_t)bh * 64 * 2048 + split * 1024;

  // Q B-frags: lane provides Q[qrow0+q][s*16 + hi*8 + j]
  bf16x8 qa[4];
#pragma unroll
  for (int s = 0; s < 4; s++)
    qa[s] = *(const bf16x8*)(Q + ((size_t)bh * 2048 + qrow0 + q) * 64 + s * 16 + hi * 8);

  // loop-invariant LDS read offsets; identical formula for K (QK^T) and V (PV)
  int off0[4], off1[4];
#pragma unroll
  for (int se = 0; se < 4; se++) {
    int gk = se * 2 + hi;
    off0[se] = q * 64 + ((gk ^ (q & 7)) * 8);
    off1[se] = (32 + q) * 64 + ((gk ^ (q & 7)) * 8);
  }

  // staging lane constants: slots sl = (i*4+w)*64 + l, i=0,1
  int sl0 = (w)*64 + l, sl1 = (4 + w) * 64 + l;
  int r0 = sl0 >> 3, g0 = (sl0 & 7) ^ (r0 & 7);
  int r1 = sl1 >> 3, g1 = (sl1 & 7) ^ (r1 & 7);
  const unsigned short* Kg0 = Kbase + (size_t)r0 * 64 + g0 * 8;
  const unsigned short* Kg1 = Kbase + (size_t)r1 * 64 + g1 * 8;
  const unsigned short* Vg0 = Vbase + (size_t)r0 * 2048 + g0 * 8;
  const unsigned short* Vg1 = Vbase + (size_t)r1 * 2048 + g1 * 8;

  f32x16 acc0, acc1;
  for (int i = 0; i < 16; i++) { acc0[i] = 0.f; acc1[i] = 0.f; }
  float m = -INFINITY, sum = 0.f;

  auto stage = [&](int buf, int kt) {
    gload_lds16(Kg0 + (size_t)kt * 64, &Ks[buf][w * 512]);
    gload_lds16(Kg1 + (size_t)kt * 64, &Ks[buf][(4 + w) * 512]);
    gload_lds16(Vg0 + kt, &Vs[buf][w * 512]);
    gload_lds16(Vg1 + kt, &Vs[buf][(4 + w) * 512]);
  };

  stage(0, 0);
  __syncthreads();
  int cur = 0;
  for (int it = 0; it < 16; it++) {
    if (it < 15) stage(cur ^ 1, (it + 1) * 64);
    const unsigned short* Ksc = Ks[cur];
    const unsigned short* Vsc = Vs[cur];

    // ---- QK^T: two 32x32 S-tiles (ktoks 0..31, 32..63) ----
    f32x16 s0, s1;
    for (int i = 0; i < 16; i++) { s0[i] = 0.f; s1[i] = 0.f; }
    __builtin_amdgcn_s_setprio(1);
#pragma unroll
    for (int se = 0; se < 4; se++) {
      bf16x8 ka0 = *(const bf16x8*)&Ksc[off0[se]];
      bf16x8 ka1 = *(const bf16x8*)&Ksc[off1[se]];
      s0 = __builtin_amdgcn_mfma_f32_32x32x16_bf16(ka0, qa[se], s0, 0, 0, 0);
      s1 = __builtin_amdgcn_mfma_f32_32x32x16_bf16(ka1, qa[se], s1, 0, 0, 0);
    }
    __builtin_amdgcn_s_setprio(0);

    // ---- in-register online softmax (log2 domain, defer-max THR=8) ----
    // max3-fused reduction tree (clang fuses fmaxf(fmaxf(a,b),c) -> v_max3_f32)
    float t0 = fmaxf(fmaxf(s0[0],  s0[1]),  s0[2]);
    float t1 = fmaxf(fmaxf(s0[3],  s0[4]),  s0[5]);
    float t2 = fmaxf(fmaxf(s0[6],  s0[7]),  s0[8]);
    float t3 = fmaxf(fmaxf(s0[9],  s0[10]), s0[11]);
    float t4 = fmaxf(fmaxf(s0[12], s0[13]), s0[14]);
    float t5 = fmaxf(fmaxf(s0[15], s1[0]),  s1[1]);
    float t6 = fmaxf(fmaxf(s1[2],  s1[3]),  s1[4]);
    float t7 = fmaxf(fmaxf(s1[5],  s1[6]),  s1[7]);
    float t8 = fmaxf(fmaxf(s1[8],  s1[9]),  s1[10]);
    float t9 = fmaxf(fmaxf(s1[11], s1[12]), s1[13]);
    float ta = fmaxf(s1[14], s1[15]);
    t0 = fmaxf(fmaxf(t0, t1), t2);
    t3 = fmaxf(fmaxf(t3, t4), t5);
    t6 = fmaxf(fmaxf(t6, t7), t8);
    t9 = fmaxf(t9, ta);
    float tm = fmaxf(fmaxf(t0, t3), fmaxf(t6, t9));
    tm = fmaxf(tm, __shfl_xor(tm, 32));
    if (!__all(tm - m <= 8.f)) {
      float mn = fmaxf(m, tm);
      float alpha = exp2f(m - mn);
      sum *= alpha;
#pragma unroll
      for (int i = 0; i < 16; i++) { acc0[i] *= alpha; acc1[i] *= alpha; }
      m = mn;
    }
    float p0[16], p1[16], ts = 0.f;
#pragma unroll
    for (int i = 0; i < 16; i++) {
      p0[i] = exp2f(s0[i] - m); p1[i] = exp2f(s1[i] - m);
      ts += p0[i] + p1[i];
    }
    ts += __shfl_xor(ts, 32);
    sum += ts;

    // ---- P B-frags: cvt_pk (1 instr / 2 values), own regs, no shuffles ----
    bf16x8 pf[4];
#pragma unroll
    for (int n = 0; n < 4; n++) {
      const float* p = (n < 2) ? p0 : p1;
      int o = (n & 1) * 8;
      u32x4 t;
#pragma unroll
      for (int j = 0; j < 4; j++) t[j] = cvtpk(p[o + 2 * j], p[o + 2 * j + 1]);
      pf[n] = __builtin_bit_cast(bf16x8, t);
    }

    // ---- PV: O^T += V^T . P^T ----
    __builtin_amdgcn_s_setprio(1);
#pragma unroll
    for (int n = 0; n < 4; n++) {
      bf16x8 va0 = *(const bf16x8*)&Vsc[off0[n]];
      bf16x8 va1 = *(const bf16x8*)&Vsc[off1[n]];
      acc0 = __builtin_amdgcn_mfma_f32_32x32x16_bf16(va0, pf[n], acc0, 0, 0, 0);
      acc1 = __builtin_amdgcn_mfma_f32_32x32x16_bf16(va1, pf[n], acc1, 0, 0, 0);
    }
    __builtin_amdgcn_s_setprio(0);
    __syncthreads();     // drains prefetch vmcnt; buffer swap safe
    cur ^= 1;
  }

  // ---- epilogue: unnormalized partial O^T (bf16, cvt_pk) + m/sum (f32) ----
  size_t prow = (size_t)(split * 32 + bh) * 2048 + qrow0 + q;
  unsigned short* Op = Opart + prow * 64;
#pragma unroll
  for (int et = 0; et < 2; et++) {
    const f32x16& a = et ? acc1 : acc0;
#pragma unroll
    for (int qd = 0; qd < 4; qd++) {
      int e0 = et * 32 + 4 * hi + qd * 8;
      u32x2 t;
      t[0] = cvtpk(a[qd * 4 + 0], a[qd * 4 + 1]);
      t[1] = cvtpk(a[qd * 4 + 2], a[qd * 4 + 3]);
      *(bf16x4*)&Op[e0] = __builtin_bit_cast(bf16x4, t);
    }
  }
  if (hi == 0) {
    ms[prow * 2] = m;
    ms[prow * 2 + 1] = sum;
  }
}

extern "C" void kernel_launch(void* const* d_in, const int* in_sizes, int n_in,
                              void* d_out, int out_size, void* d_ws, size_t ws_size,
                              hipStream_t stream) {
  const float* x      = (const float*)d_in[0];
  const float* pos    = (const float*)d_in[1];
  const float* cond   = (const float*)d_in[2];
  const float* norm_w = (const float*)d_in[3];
  const float* qkv_w  = (const float*)d_in[4];
  const float* out_w  = (const float*)d_in[5];
  const float* scale  = (const float*)d_in[6];
  const float* freqs  = (const float*)d_in[7];
  float* out = (float*)d_out;
  char* ws = (char*)d_ws;

  const size_t o_ada    = 0;
  const size_t o_rowsum = 8192;
  const size_t o_scales = 24576;
  const size_t o_Wq     = 24832;
  const size_t o_Wo     = o_Wq + 3072ull*1024*2;
  const size_t o_Aq     = o_Wo + 1024ull*1024*2;
  const size_t o_qkv    = o_Aq + 4096ull*1024*2;     // 24 MB region
  const size_t o_K      = o_qkv + 4096ull*3072*2;
  const size_t o_VT     = o_K + 2ull*16*2048*64*2;

  float* ada            = (float*)(ws + o_ada);
  float* rowsum         = (float*)(ws + o_rowsum);
  float* scales         = (float*)(ws + o_scales);
  unsigned short* Wq    = (unsigned short*)(ws + o_Wq);
  unsigned short* Wo    = (unsigned short*)(ws + o_Wo);
  unsigned short* Aq    = (unsigned short*)(ws + o_Aq);
  unsigned short* Qb    = Aq;                        // reuse after GEMM1
  unsigned short* qkv   = (unsigned short*)(ws + o_qkv);
  unsigned short* Opart = (unsigned short*)(ws + o_qkv);            // reuse (16.78 MB)
  float* msb            = (float*)(ws + o_qkv + 2ull*32*2048*64*2); // 2.1 MB
  unsigned short* Kb    = (unsigned short*)(ws + o_K);
  unsigned short* Oq    = Kb;                        // reuse after attention
  unsigned short* VT    = (unsigned short*)(ws + o_VT);

  wred_k<<<4096, 256, 0, stream>>>(qkv_w, out_w, rowsum);
  finalize_k<<<1, 256, 0, stream>>>(rowsum, scales);
  wquant_k<<<4096, 256, 0, stream>>>(qkv_w, out_w, scales, Wq, Wo);
  ada_k<<<dim3(256, 2), 256, 0, stream>>>(cond, norm_w, ada);
  rmsq_k<<<4096, 256, 0, stream>>>(x, ada, Aq);
  gemm_bt<<<dim3(32, 24), 256, 0, stream>>>(Aq, Wq, 3072, 1024, 0, nullptr, nullptr, qkv);
  rope_k<<<16384, 256, 0, stream>>>(qkv, pos, scale, freqs, Qb, Kb);
  vtrans_k<<<dim3(32, 32), 256, 0, stream>>>(qkv, VT);
  attn_k<<<1024, 256, 0, stream>>>(Qb, Kb, VT, Opart, msb);
  oquant_k<<<4096, 256, 0, stream>>>(Opart, msb, Oq);
  gemm_bt<<<dim3(32, 8), 256, 0, stream>>>(Oq, Wo, 1024, 1024, 1, x, out, nullptr);
}

// Round 9
// 180.201 us; speedup vs baseline: 1.9406x; 1.0035x over previous
//
#include <hip/hip_runtime.h>
#include <hip/hip_bf16.h>
#include <math.h>

typedef __attribute__((ext_vector_type(8))) short bf16x8;
typedef __attribute__((ext_vector_type(4))) short bf16x4;
typedef __attribute__((ext_vector_type(4))) float f32x4;
typedef __attribute__((ext_vector_type(16))) float f32x16;
typedef __attribute__((ext_vector_type(4))) unsigned u32x4;
typedef __attribute__((ext_vector_type(2))) unsigned u32x2;

#define DEV static __device__ __forceinline__
#define LOG2E 1.4426950408889634f

DEV unsigned short f2bf(float f) {
  unsigned int u = __float_as_uint(f);
  u += 0x7FFFu + ((u >> 16) & 1u);   // RNE, inputs finite
  return (unsigned short)(u >> 16);
}
DEV float bf2f(unsigned short h) { return __uint_as_float(((unsigned int)h) << 16); }
// packed f32x2 -> bf16x2 (RNE), 1 instr; low word = first arg (T12 recipe)
DEV unsigned cvtpk(float lo, float hi) {
  unsigned r;
  asm("v_cvt_pk_bf16_f32 %0, %1, %2" : "=v"(r) : "v"(lo), "v"(hi));
  return r;
}
DEV float wsum(float v) { for (int o = 32; o; o >>= 1) v += __shfl_xor(v, o); return v; }
DEV float wmaxr(float v) { for (int o = 32; o; o >>= 1) v = fmaxf(v, __shfl_xor(v, o)); return v; }

// async global->LDS, 16B per lane; dest = wave-uniform base + lane*16
DEV void gload_lds16(const void* g, void* s) {
  __builtin_amdgcn_global_load_lds(
      (const __attribute__((address_space(1))) unsigned int*)g,
      (__attribute__((address_space(3))) unsigned int*)s, 16, 0, 0);
}

// ---------- weight-quant scale: per-row |w| sums ----------
__global__ __launch_bounds__(256) void wred_k(const float* __restrict__ qw,
                                              const float* __restrict__ ow,
                                              float* __restrict__ rowsum) {
  int row = blockIdx.x;  // 0..3071 -> qkv_w, 3072..4095 -> out_w
  const float* p = (row < 3072) ? (qw + (size_t)row * 1024)
                                : (ow + (size_t)(row - 3072) * 1024);
  f32x4 v = *(const f32x4*)&p[threadIdx.x * 4];
  float s = fabsf(v[0]) + fabsf(v[1]) + fabsf(v[2]) + fabsf(v[3]);
  s = wsum(s);
  __shared__ float sh[4];
  if ((threadIdx.x & 63) == 0) sh[threadIdx.x >> 6] = s;
  __syncthreads();
  if (threadIdx.x == 0) rowsum[row] = sh[0] + sh[1] + sh[2] + sh[3];
}

__global__ __launch_bounds__(256) void finalize_k(const float* __restrict__ rowsum,
                                                  float* __restrict__ scales) {
  float s1 = 0.f, s2 = 0.f;
  for (int i = threadIdx.x; i < 3072; i += 256) s1 += rowsum[i];
  for (int i = threadIdx.x; i < 1024; i += 256) s2 += rowsum[3072 + i];
  s1 = wsum(s1); s2 = wsum(s2);
  __shared__ float sh1[4], sh2[4];
  if ((threadIdx.x & 63) == 0) { sh1[threadIdx.x >> 6] = s1; sh2[threadIdx.x >> 6] = s2; }
  __syncthreads();
  if (threadIdx.x == 0) {
    float m1 = fmaxf((sh1[0] + sh1[1] + sh1[2] + sh1[3]) / (3072.f * 1024.f), 1e-5f);
    float m2 = fmaxf((sh2[0] + sh2[1] + sh2[2] + sh2[3]) / (1024.f * 1024.f), 1e-5f);
    scales[0] = m1; scales[1] = 1.f / m1;
    scales[2] = m2; scales[3] = 1.f / m2;
  }
}

// ternary-quantize both weight matrices -> bf16 (4.19M elems = 4096*256*4)
__global__ __launch_bounds__(256) void wquant_k(const float* __restrict__ qw,
                                                const float* __restrict__ ow,
                                                const float* __restrict__ scales,
                                                unsigned short* __restrict__ Wq,
                                                unsigned short* __restrict__ Wo) {
  int i0 = (blockIdx.x * 256 + threadIdx.x) * 4;
  if (i0 < 3072 * 1024) {
    f32x4 v = *(const f32x4*)&qw[i0];
    bf16x4 u;
    for (int j = 0; j < 4; j++)
      u[j] = (short)f2bf(fminf(fmaxf(rintf(v[j] * scales[1]), -1.f), 1.f) * scales[0]);
    *(bf16x4*)&Wq[i0] = u;
  } else {
    int k = i0 - 3072 * 1024;
    f32x4 v = *(const f32x4*)&ow[k];
    bf16x4 u;
    for (int j = 0; j < 4; j++)
      u[j] = (short)f2bf(fminf(fmaxf(rintf(v[j] * scales[3]), -1.f), 1.f) * scales[2]);
    *(bf16x4*)&Wo[k] = u;
  }
}

// ---------- ada = 1 + cond @ norm_w^T ----------
__global__ __launch_bounds__(256) void ada_k(const float* __restrict__ cond,
                                             const float* __restrict__ nw,
                                             float* __restrict__ ada) {
  int j = blockIdx.x * 4 + (threadIdx.x >> 6);
  int b = blockIdx.y;
  int l = threadIdx.x & 63;
  const float* cp = cond + b * 1024;
  const float* wp = nw + (size_t)j * 1024;
  float s = 0.f;
  for (int c = l; c < 1024; c += 64) s += cp[c] * wp[c];
  s = wsum(s);
  if (l == 0) ada[b * 1024 + j] = 1.f + s;
}

// ---------- RMSNorm(ada) + act_quant -> bf16 ----------
__global__ __launch_bounds__(256) void rmsq_k(const float* __restrict__ x,
                                              const float* __restrict__ ada,
                                              unsigned short* __restrict__ Aq) {
  int row = blockIdx.x;          // b*2048 + t
  int b = row >> 11;
  const float* xr = x + (size_t)row * 1024;
  const float* ar = ada + b * 1024;
  int t4 = threadIdx.x * 4;
  f32x4 v = *(const f32x4*)&xr[t4];
  float ss = v[0]*v[0] + v[1]*v[1] + v[2]*v[2] + v[3]*v[3];
  ss = wsum(ss);
  __shared__ float sh[4], sh2[4];
  if ((threadIdx.x & 63) == 0) sh[threadIdx.x >> 6] = ss;
  __syncthreads();
  float inv = rsqrtf((sh[0] + sh[1] + sh[2] + sh[3]) * (1.f / 1024.f) + 1e-6f);
  f32x4 a = *(const f32x4*)&ar[t4];
  float xn[4]; float mx = 0.f;
  for (int i = 0; i < 4; i++) { xn[i] = v[i] * a[i] * inv; mx = fmaxf(mx, fabsf(xn[i])); }
  mx = wmaxr(mx);
  if ((threadIdx.x & 63) == 0) sh2[threadIdx.x >> 6] = mx;
  __syncthreads();
  float rmax = fmaxf(fmaxf(sh2[0], sh2[1]), fmaxf(sh2[2], sh2[3]));
  float s = 127.f / fmaxf(rmax, 1e-5f);
  float is = 1.f / s;
  bf16x4 u;
  for (int i = 0; i < 4; i++)
    u[i] = (short)f2bf(fminf(fmaxf(rintf(xn[i] * s), -128.f), 127.f) * is);
  *(bf16x4*)&Aq[(size_t)row * 1024 + t4] = u;
}

// ---------- combine split-K partials + act_quant ----------
__global__ __launch_bounds__(256) void oquant_k(const unsigned short* __restrict__ Opart,
                                                const float* __restrict__ ms,
                                                unsigned short* __restrict__ Oq) {
  int row = blockIdx.x;            // b*2048 + t
  int b = row >> 11, qrow = row & 2047;
  int t4 = threadIdx.x * 4;
  int h = t4 >> 6, e0 = t4 & 63;
  int bh = b * 16 + h;
  size_t i0 = (size_t)bh * 2048 + qrow;             // split 0
  size_t i1 = (size_t)(32 + bh) * 2048 + qrow;      // split 1
  float m0 = ms[i0 * 2], s0 = ms[i0 * 2 + 1];
  float m1 = ms[i1 * 2], s1 = ms[i1 * 2 + 1];
  float mm = fmaxf(m0, m1);
  float a0 = exp2f(m0 - mm), a1 = exp2f(m1 - mm);
  float den = s0 * a0 + s1 * a1;
  float w0 = a0 / den, w1 = a1 / den;
  bf16x4 o0 = *(const bf16x4*)&Opart[i0 * 64 + e0];
  bf16x4 o1 = *(const bf16x4*)&Opart[i1 * 64 + e0];
  float v[4]; float mx = 0.f;
  for (int i = 0; i < 4; i++) {
    v[i] = bf2f((unsigned short)o0[i]) * w0 + bf2f((unsigned short)o1[i]) * w1;
    mx = fmaxf(mx, fabsf(v[i]));
  }
  mx = wmaxr(mx);
  __shared__ float sh[4];
  if ((threadIdx.x & 63) == 0) sh[threadIdx.x >> 6] = mx;
  __syncthreads();
  float rmax = fmaxf(fmaxf(sh[0], sh[1]), fmaxf(sh[2], sh[3]));
  float s = 127.f / fmaxf(rmax, 1e-5f);
  float is = 1.f / s;
  bf16x4 u;
  for (int i = 0; i < 4; i++)
    u[i] = (short)f2bf(fminf(fmaxf(rintf(v[i] * s), -128.f), 127.f) * is);
  *(bf16x4*)&Oq[(size_t)row * 1024 + t4] = u;
}

// ---------- C[M][N] = A[M][K] * B[N][K]^T, 128x128 tile, BK=64, gl_lds + XOR swizzle ----------
// (256,3): gemm1's 768 blocks land exactly 3/CU (one full round, no half-empty tail).
__global__ __launch_bounds__(256, 3) void gemm_bt(const unsigned short* __restrict__ A,
                                                  const unsigned short* __restrict__ Bw,
                                                  int N, int K, int mode,
                                                  const float* __restrict__ skip,
                                                  float* __restrict__ outF,
                                                  unsigned short* __restrict__ outB) {
  __shared__ unsigned short As[128 * 64];
  __shared__ unsigned short Bs[128 * 64];
  int tid = threadIdx.x;
  int w = tid >> 6, l = tid & 63;
  int q = l & 15, g = l >> 4;
  int tm = blockIdx.x * 128, tn = blockIdx.y * 128;
  int wr = w >> 1, wc = w & 1;          // wave's 64x64 quadrant
  f32x4 zero = {0.f, 0.f, 0.f, 0.f};
  f32x4 acc[4][4];
#pragma unroll
  for (int m = 0; m < 4; m++)
#pragma unroll
    for (int n = 0; n < 4; n++) acc[m][n] = zero;
  int srow = l >> 3;
  int sg = (l & 7) ^ srow;              // inverse-swizzled source granule
  const unsigned short* Ag = A + (size_t)(tm + srow) * K + sg * 8;
  const unsigned short* Bg = Bw + (size_t)(tn + srow) * K + sg * 8;
  for (int k0 = 0; k0 < K; k0 += 64) {
#pragma unroll
    for (int ra = 0; ra < 4; ra++) {
      size_t roff = (size_t)((w * 4 + ra) * 8) * K + k0;
      gload_lds16(Ag + roff, &As[(w * 4 + ra) * 512]);
      gload_lds16(Bg + roff, &Bs[(w * 4 + ra) * 512]);
    }
    __syncthreads();
#pragma unroll
    for (int kk = 0; kk < 2; kk++) {
      int gs = ((kk * 4 + g) ^ (q & 7)) * 8;
      bf16x8 af[4], bfr[4];
#pragma unroll
      for (int m = 0; m < 4; m++)
        af[m] = *(const bf16x8*)&As[(wr * 64 + m * 16 + q) * 64 + gs];
#pragma unroll
      for (int n = 0; n < 4; n++)
        bfr[n] = *(const bf16x8*)&Bs[(wc * 64 + n * 16 + q) * 64 + gs];
#pragma unroll
      for (int m = 0; m < 4; m++)
#pragma unroll
        for (int n = 0; n < 4; n++)
          acc[m][n] = __builtin_amdgcn_mfma_f32_16x16x32_bf16(af[m], bfr[n], acc[m][n], 0, 0, 0);
    }
    __syncthreads();
  }
#pragma unroll
  for (int m = 0; m < 4; m++) {
#pragma unroll
    for (int n = 0; n < 4; n++) {
      int col = tn + wc * 64 + n * 16 + q;
#pragma unroll
      for (int r = 0; r < 4; r++) {
        int row = tm + wr * 64 + m * 16 + g * 4 + r;
        float vv = acc[m][n][r];
        if (mode == 0) outB[(size_t)row * N + col] = f2bf(vv);
        else { size_t idx = (size_t)row * N + col; outF[idx] = vv + skip[idx]; }
      }
    }
  }
}

// ---------- qk-norm + RoPE (Q pre-scaled by log2(e) for exp2-softmax) ----------
__global__ __launch_bounds__(256) void rope_k(const unsigned short* __restrict__ qkv,
                                              const float* __restrict__ pos,
                                              const float* __restrict__ scale,
                                              const float* __restrict__ freqs,
                                              unsigned short* __restrict__ Qo,
                                              unsigned short* __restrict__ Ko) {
  int tid = threadIdx.x;
  int w = tid >> 6, l = tid & 63;
  int gw = blockIdx.x * 4 + w;            // b*32768 + t*16 + h
  int h = gw & 15, t = (gw >> 4) & 2047, b = gw >> 15;
  const unsigned short* base = qkv + ((size_t)(b * 2048 + t)) * 3072 + h * 64 + l;
  float qv = bf2f(base[0]);
  float kv = bf2f(base[1024]);
  float sq = qv * qv, sk = kv * kv;
  for (int o = 32; o; o >>= 1) { sq += __shfl_xor(sq, o); sk += __shfl_xor(sk, o); }
  float ssc = sqrtf(scale[h]);
  float fq = ssc * rsqrtf(sq + 1e-6f);
  float fk = ssc * rsqrtf(sk + 1e-6f);
  float qn = qv * fq, kn = kv * fk;
  int e = l;
  int idx24 = (e < 24) ? e : e - 24;
  int partner = (e < 24) ? e + 24 : ((e < 48) ? e - 24 : e);
  float qo = __shfl(qn, partner), ko = __shfl(kn, partner);
  float qr = qn, kr = kn;
  if (e < 48) {
    int a = idx24 >> 3, f = idx24 & 7;
    float th = pos[((size_t)(b * 2048 + t)) * 3 + a] * freqs[h * 8 + f];
    float sn, cs; __sincosf(th, &sn, &cs);
    if (e < 24) { qr = qn * cs - qo * sn; kr = kn * cs - ko * sn; }
    else        { qr = qn * cs + qo * sn; kr = kn * cs + ko * sn; }
  }
  size_t oi = ((size_t)((b * 16 + h) * 2048 + t)) * 64 + e;
  Qo[oi] = f2bf(qr * LOG2E);   // pre-scale: softmax uses exp2
  Ko[oi] = f2bf(kr);
}

// ---------- V transpose: VT[b][h][e][t'], t' = t with bits2<->3 swapped in 16-blk ----------
// The swap bakes the PV k-permutation into VT so attn needs ZERO cross-lane P exchange.
__global__ __launch_bounds__(256) void vtrans_k(const unsigned short* __restrict__ qkv,
                                                unsigned short* __restrict__ VT) {
  __shared__ unsigned short tile[64][72];
  int tt = blockIdx.x, bh = blockIdx.y;
  int b = bh >> 4, h = bh & 15;
  int tid = threadIdx.x;
  for (int ro = 0; ro < 2; ro++) {
    int r = ro * 32 + (tid >> 3);
    int c = (tid & 7) * 8;
    *(bf16x8*)&tile[r][c] =
        *(const bf16x8*)(qkv + ((size_t)(b * 2048 + tt * 64 + r)) * 3072 + 2048 + h * 64 + c);
  }
  __syncthreads();
  int e = tid >> 2;
  int tc = (tid & 3) * 16;
  bf16x8 o0, o1;
#pragma unroll
  for (int i = 0; i < 4; i++) {
    o0[i]     = (short)tile[tc + i][e];        // dst 0..3   <- tok 0..3
    o0[4 + i] = (short)tile[tc + 8 + i][e];    // dst 4..7   <- tok 8..11
    o1[i]     = (short)tile[tc + 4 + i][e];    // dst 8..11  <- tok 4..7
    o1[4 + i] = (short)tile[tc + 12 + i][e];   // dst 12..15 <- tok 12..15
  }
  unsigned short* dst = VT + ((size_t)(bh * 64 + e)) * 2048 + tt * 64 + tc;
  *(bf16x8*)dst = o0;
  *(bf16x8*)(dst + 8) = o1;
}

// ---------- flash attention v7: 8-wave blocks, 32x32 MFMA, zero-shuffle PV ----------
// grid 512 = split(2) x bh(32) x qg(8); block 512 = 8 waves; wave = 32 Q-rows.
// 8 waves share one K/V double-buffer: per-wave staging halved, 16 waves/CU resident.
__global__ __launch_bounds__(512, 4) void attn_k(const unsigned short* __restrict__ Q,
                                                 const unsigned short* __restrict__ K,
                                                 const unsigned short* __restrict__ VT,
                                                 unsigned short* __restrict__ Opart,
                                                 float* __restrict__ ms) {
  __shared__ unsigned short Ks[2][64 * 64];   // [ktok][e], granule ^= (row&7)
  __shared__ unsigned short Vs[2][64 * 64];   // [e][ktok'], granule ^= (row&7)
  int tid = threadIdx.x;
  int w = tid >> 6, l = tid & 63;
  int q = l & 31, hi = l >> 5;
  int bx = blockIdx.x;
  int qg = bx & 7;
  int bh = (bx >> 3) & 31;
  int split = bx >> 8;
  int qrow0 = qg * 256 + w * 32;
  const unsigned short* Kbase = K + (size_t)bh * 2048 * 64 + (size_t)split * 1024 * 64;
  const unsigned short* Vbase = VT + (size_t)bh * 64 * 2048 + split * 1024;

  // Q B-frags: lane provides Q[qrow0+q][s*16 + hi*8 + j]
  bf16x8 qa[4];
#pragma unroll
  for (int s = 0; s < 4; s++)
    qa[s] = *(const bf16x8*)(Q + ((size_t)bh * 2048 + qrow0 + q) * 64 + s * 16 + hi * 8);

  // loop-invariant LDS read offsets; identical formula for K (QK^T) and V (PV)
  int off0[4], off1[4];
#pragma unroll
  for (int se = 0; se < 4; se++) {
    int gk = se * 2 + hi;
    off0[se] = q * 64 + ((gk ^ (q & 7)) * 8);
    off1[se] = (32 + q) * 64 + ((gk ^ (q & 7)) * 8);
  }

  // staging: one 16B slot per lane per buffer (512 lanes x 16B = 8KB tile)
  int sl = w * 64 + l;
  int r0 = sl >> 3, g0 = (sl & 7) ^ (r0 & 7);
  const unsigned short* Kg0 = Kbase + (size_t)r0 * 64 + g0 * 8;
  const unsigned short* Vg0 = Vbase + (size_t)r0 * 2048 + g0 * 8;

  f32x16 acc0, acc1;
  for (int i = 0; i < 16; i++) { acc0[i] = 0.f; acc1[i] = 0.f; }
  float m = -INFINITY, sum = 0.f;

  auto stage = [&](int buf, int kt) {
    gload_lds16(Kg0 + (size_t)kt * 64, &Ks[buf][w * 512]);
    gload_lds16(Vg0 + kt, &Vs[buf][w * 512]);
  };

  stage(0, 0);
  __syncthreads();
  int cur = 0;
  for (int it = 0; it < 16; it++) {
    if (it < 15) stage(cur ^ 1, (it + 1) * 64);
    const unsigned short* Ksc = Ks[cur];
    const unsigned short* Vsc = Vs[cur];

    // ---- QK^T: two 32x32 S-tiles (ktoks 0..31, 32..63) ----
    f32x16 s0, s1;
    for (int i = 0; i < 16; i++) { s0[i] = 0.f; s1[i] = 0.f; }
    __builtin_amdgcn_s_setprio(1);
#pragma unroll
    for (int se = 0; se < 4; se++) {
      bf16x8 ka0 = *(const bf16x8*)&Ksc[off0[se]];
      bf16x8 ka1 = *(const bf16x8*)&Ksc[off1[se]];
      s0 = __builtin_amdgcn_mfma_f32_32x32x16_bf16(ka0, qa[se], s0, 0, 0, 0);
      s1 = __builtin_amdgcn_mfma_f32_32x32x16_bf16(ka1, qa[se], s1, 0, 0, 0);
    }
    __builtin_amdgcn_s_setprio(0);

    // ---- in-register online softmax (log2 domain, defer-max THR=8) ----
    float t0 = fmaxf(fmaxf(s0[0],  s0[1]),  s0[2]);
    float t1 = fmaxf(fmaxf(s0[3],  s0[4]),  s0[5]);
    float t2 = fmaxf(fmaxf(s0[6],  s0[7]),  s0[8]);
    float t3 = fmaxf(fmaxf(s0[9],  s0[10]), s0[11]);
    float t4 = fmaxf(fmaxf(s0[12], s0[13]), s0[14]);
    float t5 = fmaxf(fmaxf(s0[15], s1[0]),  s1[1]);
    float t6 = fmaxf(fmaxf(s1[2],  s1[3]),  s1[4]);
    float t7 = fmaxf(fmaxf(s1[5],  s1[6]),  s1[7]);
    float t8 = fmaxf(fmaxf(s1[8],  s1[9]),  s1[10]);
    float t9 = fmaxf(fmaxf(s1[11], s1[12]), s1[13]);
    float ta = fmaxf(s1[14], s1[15]);
    t0 = fmaxf(fmaxf(t0, t1), t2);
    t3 = fmaxf(fmaxf(t3, t4), t5);
    t6 = fmaxf(fmaxf(t6, t7), t8);
    t9 = fmaxf(t9, ta);
    float tm = fmaxf(fmaxf(t0, t3), fmaxf(t6, t9));
    tm = fmaxf(tm, __shfl_xor(tm, 32));
    if (!__all(tm - m <= 8.f)) {
      float mn = fmaxf(m, tm);
      float alpha = exp2f(m - mn);
      sum *= alpha;
#pragma unroll
      for (int i = 0; i < 16; i++) { acc0[i] *= alpha; acc1[i] *= alpha; }
      m = mn;
    }
    float p0[16], p1[16], ts = 0.f;
#pragma unroll
    for (int i = 0; i < 16; i++) {
      p0[i] = exp2f(s0[i] - m); p1[i] = exp2f(s1[i] - m);
      ts += p0[i] + p1[i];
    }
    ts += __shfl_xor(ts, 32);
    sum += ts;

    // ---- P B-frags: cvt_pk (1 instr / 2 values), own regs, no shuffles ----
    bf16x8 pf[4];
#pragma unroll
    for (int n = 0; n < 4; n++) {
      const float* p = (n < 2) ? p0 : p1;
      int o = (n & 1) * 8;
      u32x4 t;
#pragma unroll
      for (int j = 0; j < 4; j++) t[j] = cvtpk(p[o + 2 * j], p[o + 2 * j + 1]);
      pf[n] = __builtin_bit_cast(bf16x8, t);
    }

    // ---- PV: O^T += V^T . P^T ----
    __builtin_amdgcn_s_setprio(1);
#pragma unroll
    for (int n = 0; n < 4; n++) {
      bf16x8 va0 = *(const bf16x8*)&Vsc[off0[n]];
      bf16x8 va1 = *(const bf16x8*)&Vsc[off1[n]];
      acc0 = __builtin_amdgcn_mfma_f32_32x32x16_bf16(va0, pf[n], acc0, 0, 0, 0);
      acc1 = __builtin_amdgcn_mfma_f32_32x32x16_bf16(va1, pf[n], acc1, 0, 0, 0);
    }
    __builtin_amdgcn_s_setprio(0);
    __syncthreads();     // drains prefetch vmcnt; buffer swap safe
    cur ^= 1;
  }

  // ---- epilogue: unnormalized partial O^T (bf16, cvt_pk) + m/sum (f32) ----
  size_t prow = (size_t)(split * 32 + bh) * 2048 + qrow0 + q;
  unsigned short* Op = Opart + prow * 64;
#pragma unroll
  for (int et = 0; et < 2; et++) {
    const f32x16& a = et ? acc1 : acc0;
#pragma unroll
    for (int qd = 0; qd < 4; qd++) {
      int e0 = et * 32 + 4 * hi + qd * 8;
      u32x2 t;
      t[0] = cvtpk(a[qd * 4 + 0], a[qd * 4 + 1]);
      t[1] = cvtpk(a[qd * 4 + 2], a[qd * 4 + 3]);
      *(bf16x4*)&Op[e0] = __builtin_bit_cast(bf16x4, t);
    }
  }
  if (hi == 0) {
    ms[prow * 2] = m;
    ms[prow * 2 + 1] = sum;
  }
}

extern "C" void kernel_launch(void* const* d_in, const int* in_sizes, int n_in,
                              void* d_out, int out_size, void* d_ws, size_t ws_size,
                              hipStream_t stream) {
  const float* x      = (const float*)d_in[0];
  const float* pos    = (const float*)d_in[1];
  const float* cond   = (const float*)d_in[2];
  const float* norm_w = (const float*)d_in[3];
  const float* qkv_w  = (const float*)d_in[4];
  const float* out_w  = (const float*)d_in[5];
  const float* scale  = (const float*)d_in[6];
  const float* freqs  = (const float*)d_in[7];
  float* out = (float*)d_out;
  char* ws = (char*)d_ws;

  const size_t o_ada    = 0;
  const size_t o_rowsum = 8192;
  const size_t o_scales = 24576;
  const size_t o_Wq     = 24832;
  const size_t o_Wo     = o_Wq + 3072ull*1024*2;
  const size_t o_Aq     = o_Wo + 1024ull*1024*2;
  const size_t o_qkv    = o_Aq + 4096ull*1024*2;     // 24 MB region
  const size_t o_K      = o_qkv + 4096ull*3072*2;
  const size_t o_VT     = o_K + 2ull*16*2048*64*2;

  float* ada            = (float*)(ws + o_ada);
  float* rowsum         = (float*)(ws + o_rowsum);
  float* scales         = (float*)(ws + o_scales);
  unsigned short* Wq    = (unsigned short*)(ws + o_Wq);
  unsigned short* Wo    = (unsigned short*)(ws + o_Wo);
  unsigned short* Aq    = (unsigned short*)(ws + o_Aq);
  unsigned short* Qb    = Aq;                        // reuse after GEMM1
  unsigned short* qkv   = (unsigned short*)(ws + o_qkv);
  unsigned short* Opart = (unsigned short*)(ws + o_qkv);            // reuse (16.78 MB)
  float* msb            = (float*)(ws + o_qkv + 2ull*32*2048*64*2); // 2.1 MB
  unsigned short* Kb    = (unsigned short*)(ws + o_K);
  unsigned short* Oq    = Kb;                        // reuse after attention
  unsigned short* VT    = (unsigned short*)(ws + o_VT);

  wred_k<<<4096, 256, 0, stream>>>(qkv_w, out_w, rowsum);
  finalize_k<<<1, 256, 0, stream>>>(rowsum, scales);
  wquant_k<<<4096, 256, 0, stream>>>(qkv_w, out_w, scales, Wq, Wo);
  ada_k<<<dim3(256, 2), 256, 0, stream>>>(cond, norm_w, ada);
  rmsq_k<<<4096, 256, 0, stream>>>(x, ada, Aq);
  gemm_bt<<<dim3(32, 24), 256, 0, stream>>>(Aq, Wq, 3072, 1024, 0, nullptr, nullptr, qkv);
  rope_k<<<16384, 256, 0, stream>>>(qkv, pos, scale, freqs, Qb, Kb);
  vtrans_k<<<dim3(32, 32), 256, 0, stream>>>(qkv, VT);
  attn_k<<<512, 512, 0, stream>>>(Qb, Kb, VT, Opart, msb);
  oquant_k<<<4096, 256, 0, stream>>>(Opart, msb, Oq);
  gemm_bt<<<dim3(32, 8), 256, 0, stream>>>(Oq, Wo, 1024, 1024, 1, x, out, nullptr);
}